// Round 3
// baseline (2309.533 us; speedup 1.0000x reference)
//
#include <hip/hip_runtime.h>
#include <cstdint>

typedef unsigned short u16;
typedef unsigned int   u32;
using short8 = __attribute__((ext_vector_type(8))) short;
using f32x4  = __attribute__((ext_vector_type(4))) float;

#define S_   2048
#define D_   1024
#define NTOK 4096   /* B*S */

__device__ __forceinline__ u16 f2bf(float f){
  u32 u = __float_as_uint(f);
  u32 r = u + 0x7fffu + ((u >> 16) & 1u);   // RNE
  return (u16)(r >> 16);
}
__device__ __forceinline__ float bf2f(u16 h){
  return __uint_as_float(((u32)h) << 16);
}
__device__ __forceinline__ void gld16(const void* g, void* l){
  __builtin_amdgcn_global_load_lds((__attribute__((address_space(1))) void*)(void*)g,
                                   (__attribute__((address_space(3))) void*)l, 16, 0, 0);
}

// ---------------------------------------------------------------------------
// bf16 MFMA GEMM (NT): C[M,N] = A[M,K] * Bt[N,K]^T, 128x128x32 tiles, 4 waves.
// F_GATHER : A rows gathered via idx (routed expert GEMM1); early-exit on cnt.
// F_SCATTER: output rows scattered via idx, facc[tok] += gv*(v+bias).
// F_PVOUT  : z = ks*8+hl; A += hl*sAz + ks*K; Bt += hl*sBz + ks*K;
//            f32 partial store at [row][hl*64+col], buffer ks via sOz.
// XCD-aware bijective block swizzle (m204) applied to the flat block id.
// ---------------------------------------------------------------------------
enum { F_OUTBF16=1, F_BIAS=2, F_RELU=4, F_RESID=8, F_GATEACC=16,
       F_GATHER=64, F_SCATTER=128, F_PVOUT=256 };

template<int FLAGS>
__global__ void __launch_bounds__(256, 4)
gemm_k(const u16* __restrict__ A, int lda, long sAz,
       const u16* __restrict__ Bt, int ldb, long sBz,
       void* __restrict__ out, int ldo, long sOz,
       const float* __restrict__ bias,
       const float* __restrict__ resid,
       const float* __restrict__ gv,
       const int* __restrict__ idx,
       const int* __restrict__ cntp,
       int K, int ncols)
{
  constexpr int BM = 128, BK = 32;
  const int tid = threadIdx.x;
  const int w = tid >> 6, l = tid & 63;
  const int wr = w >> 1, wc = w & 1;

  // bijective XCD swizzle
  const int gx = gridDim.x, gy = gridDim.y;
  const int nwg = gx*gy*gridDim.z;
  const int flat = (blockIdx.z*gy + blockIdx.y)*gx + blockIdx.x;
  const int q8 = nwg >> 3, r8 = nwg & 7, xcd = flat & 7, off8 = flat >> 3;
  const int swz = (xcd < r8) ? (xcd*(q8+1) + off8)
                             : (r8*(q8+1) + (xcd-r8)*q8 + off8);
  const int tn = swz % gx;
  const int rest = swz / gx;
  const int tm = rest % gy;
  const int z  = rest / gy;
  const int ncol0 = tn * 128;

  int cnt = 0x7fffffff;
  if constexpr (FLAGS & (F_GATHER|F_SCATTER)){
    cnt = *cntp;
    if (tm*BM >= cnt) return;
  }

  const u16 *Abase, *Btbase;
  if constexpr (FLAGS & F_PVOUT){
    Abase  = A  + (long)(z&7)*sAz + (long)(z>>3)*K + (long)tm*BM*lda;
    Btbase = Bt + (long)(z&7)*sBz + (long)(z>>3)*K + (long)ncol0*ldb;
  } else {
    Abase  = A  + (long)z*sAz + ((FLAGS & F_GATHER) ? 0L : (long)tm*BM*lda);
    Btbase = Bt + (long)z*sBz + (long)ncol0*ldb;
  }

  const int r0 = tid >> 2, seg = tid & 3;
  long aoff0, aoff1;
  if constexpr (FLAGS & F_GATHER){
    const int p0 = tm*BM + r0, p1 = p0 + 64;
    const int t0 = (p0 < cnt) ? idx[p0] : 0;
    const int t1 = (p1 < cnt) ? idx[p1] : 0;
    aoff0 = (long)t0*lda; aoff1 = (long)t1*lda;
  } else {
    aoff0 = (long)r0*lda; aoff1 = (long)(r0+64)*lda;
  }
  const u16* pA0 = Abase + aoff0 + seg*8;
  const u16* pA1 = Abase + aoff1 + seg*8;
  const u16* pB0 = Btbase + (long)r0*ldb + seg*8;
  const u16* pB1 = Btbase + (long)(r0+64)*ldb + seg*8;

  __shared__ __align__(16) u16 As[2][BM*BK];
  __shared__ __align__(16) u16 Bs[2][BM*BK];

  f32x4 zero = {0.f,0.f,0.f,0.f};
  f32x4 acc[4][4];
  #pragma unroll
  for (int i=0;i<4;i++)
    #pragma unroll
    for (int j=0;j<4;j++) acc[i][j] = zero;

  const int NK = K >> 5;

  auto stage = [&](int buf, int kt){
    const int k0 = kt*BK;
    gld16(pA0 + k0, &As[buf][(w*64)*8]);
    gld16(pA1 + k0, &As[buf][(256 + w*64)*8]);
    gld16(pB0 + k0, &Bs[buf][(w*64)*8]);
    gld16(pB1 + k0, &Bs[buf][(256 + w*64)*8]);
  };

  stage(0,0);
  __syncthreads();

  for (int kt=0; kt<NK; ++kt){
    const int cur = kt & 1, nxt = cur ^ 1;
    if (kt+1 < NK) stage(nxt, kt+1);
    short8 a[4], b[4];
    #pragma unroll
    for (int m=0;m<4;m++){
      const int arow = wr*64 + m*16 + (l & 15);
      a[m] = *(const short8*)&As[cur][arow*BK + (l>>4)*8];
    }
    #pragma unroll
    for (int n=0;n<4;n++){
      const int brow = wc*64 + n*16 + (l & 15);
      b[n] = *(const short8*)&Bs[cur][brow*BK + (l>>4)*8];
    }
    #pragma unroll
    for (int m=0;m<4;m++)
      #pragma unroll
      for (int n=0;n<4;n++)
        acc[m][n] = __builtin_amdgcn_mfma_f32_16x16x32_bf16(a[m], b[n], acc[m][n], 0, 0, 0);
    __syncthreads();
  }

  // epilogue  (C/D: col = lane&15, row = (lane>>4)*4 + reg)
  float* outf = (float*)out + (long)z*sOz;
  u16*   outh = (u16*)out + (long)z*sOz;
  float* pvf  = (float*)out + (long)(z>>3)*sOz;   // PVOUT
  const long row0 = (long)tm*BM + wr*64;
  #pragma unroll
  for (int m=0;m<4;m++){
    #pragma unroll
    for (int n=0;n<4;n++){
      const int col = ncol0 + wc*64 + n*16 + (l & 15);
      if (col < ncols){
        #pragma unroll
        for (int r=0;r<4;r++){
          const long row = row0 + m*16 + ((l>>4)*4) + r;
          float v = acc[m][n][r];
          if constexpr (FLAGS & F_BIAS) v += bias[col];
          if constexpr (FLAGS & F_RELU) v = fmaxf(v, 0.f);
          if constexpr (FLAGS & F_PVOUT){
            pvf[row*(long)ldo + (z&7)*64 + col] = v;
          } else if constexpr (FLAGS & F_SCATTER){
            if (row < cnt){
              const int tok = idx[row];
              outf[(long)tok*ldo + col] += gv[row] * v;
            }
          } else if constexpr (FLAGS & F_GATHER){
            if (row < cnt) outh[row*(long)ldo + col] = f2bf(v);
          } else if constexpr (FLAGS & F_GATEACC){
            outf[row*(long)ldo + col] += v;
          } else if constexpr (FLAGS & F_RESID){
            const long off = row*(long)ldo + col;
            outf[off] = resid[off] + v;
          } else if constexpr (FLAGS & F_OUTBF16){
            outh[row*(long)ldo + col] = f2bf(v);
          } else {
            outf[row*(long)ldo + col] = v;
          }
        }
      }
    }
  }
}

// ---------------------------------------------------------------------------
// transpose f32 [K][N] (ld=N) -> bf16 [N][K] (ld=K).  dims multiples of 32.
__global__ void tpose_k(const float* __restrict__ src, u16* __restrict__ dst,
                        int K, int N)
{
  __shared__ u16 tile[32][36];
  const int t = threadIdx.x;
  const int n0 = blockIdx.x*32, k0 = blockIdx.y*32;
  const int lr = t >> 3, lc = (t & 7) * 4;
  const float4 v = *(const float4*)&src[(long)(k0+lr)*N + n0 + lc];
  ushort4 tv; tv.x=f2bf(v.x); tv.y=f2bf(v.y); tv.z=f2bf(v.z); tv.w=f2bf(v.w);
  *(ushort4*)&tile[lr][lc] = tv;
  __syncthreads();
  ushort4 o;
  o.x = tile[lc+0][lr]; o.y = tile[lc+1][lr];
  o.z = tile[lc+2][lr]; o.w = tile[lc+3][lr];
  *(ushort4*)&dst[(long)(n0+lr)*K + k0 + lc] = o;
}

// v_bf [b][s][h*64+d] -> vt [(b*16+h)][d][s]
__global__ void vt_k(const u16* __restrict__ src, u16* __restrict__ dst)
{
  __shared__ u16 tile[32][36];
  const int t = threadIdx.x;
  const int z = blockIdx.z;            // b*16+h
  const int b = z >> 4, h = z & 15;
  const int s0 = blockIdx.x*32, d0 = blockIdx.y*32;
  const int lr = t >> 3, lc = (t & 7) * 4;
  ushort4 v = *(const ushort4*)&src[(long)(b*2048 + s0+lr)*1024 + h*64 + d0 + lc];
  *(ushort4*)&tile[lr][lc] = v;
  __syncthreads();
  ushort4 o;
  o.x = tile[lc+0][lr]; o.y = tile[lc+1][lr];
  o.z = tile[lc+2][lr]; o.w = tile[lc+3][lr];
  *(ushort4*)&dst[(long)z*131072 + (long)(d0+lr)*2048 + s0 + lc] = o;
}

// sum two f32 PV partials -> bf16 attn rows
__global__ void pvcomb_k(const float* __restrict__ p, u16* __restrict__ dst)
{
  const int row = blockIdx.x, t = threadIdx.x;
  const float2 v0 = ((const float2*)(p + (long)row*512))[t];
  const float2 v1 = ((const float2*)(p + 1048576 + (long)row*512))[t];
  u32 pk = (u32)f2bf(v0.x+v1.x) | ((u32)f2bf(v0.y+v1.y) << 16);
  *(u32*)&dst[(long)row*1024 + t*2] = pk;
}

// ---------------------------------------------------------------------------
template<bool WF32>
__global__ void rmsnorm_k(const float* __restrict__ x, const float* __restrict__ w,
                          u16* __restrict__ ob, float* __restrict__ of)
{
  const int row = blockIdx.x, t = threadIdx.x;
  const float4 v = ((const float4*)(x + (long)row*D_))[t];
  float ss = v.x*v.x + v.y*v.y + v.z*v.z + v.w*v.w;
  #pragma unroll
  for (int o=32;o>0;o>>=1) ss += __shfl_down(ss, o);
  __shared__ float red[4];
  if ((t&63)==0) red[t>>6] = ss;
  __syncthreads();
  const float scale = rsqrtf((red[0]+red[1]+red[2]+red[3])*(1.0f/D_) + 1e-6f);
  const float4 wv = ((const float4*)w)[t];
  const float o0=v.x*scale*wv.x, o1=v.y*scale*wv.y, o2=v.z*scale*wv.z, o3=v.w*scale*wv.w;
  const long base = (long)row*D_ + t*4;
  uint2 p; p.x = (u32)f2bf(o0) | ((u32)f2bf(o1)<<16);
  p.y = (u32)f2bf(o2) | ((u32)f2bf(o3)<<16);
  *(uint2*)&ob[base] = p;
  if constexpr (WF32) *(float4*)&of[base] = make_float4(o0,o1,o2,o3);
}

// qf = [q | rope(qr)], kf = [k | rope(kr)]
__global__ void rope_concat_k(const u16* __restrict__ qt, const u16* __restrict__ qrt,
                              const u16* __restrict__ kt, const u16* __restrict__ krt,
                              const float* __restrict__ fc, const float* __restrict__ fs,
                              u16* __restrict__ qf, u16* __restrict__ kf)
{
  const int idx = blockIdx.x*256 + threadIdx.x;
  const int j = idx & 31, h = (idx>>5) & 15, bs = idx >> 9;
  if (bs >= NTOK) return;
  const int s = bs & (S_-1);
  const float c = fc[s*32+j], sn = fs[s*32+j];
  const long ib = (long)bs*1024 + h*64 + 2*j;
  const long ob = (long)bs*2048 + h*128 + 2*j;
  *(u32*)&qf[ob] = *(const u32*)&qt[ib];
  *(u32*)&kf[ob] = *(const u32*)&kt[ib];
  float x0 = bf2f(qrt[ib]), x1 = bf2f(qrt[ib+1]);
  *(u32*)&qf[ob+64] = (u32)f2bf(x0*c - x1*sn) | ((u32)f2bf(x0*sn + x1*c) << 16);
  x0 = bf2f(krt[ib]); x1 = bf2f(krt[ib+1]);
  *(u32*)&kf[ob+64] = (u32)f2bf(x0*c - x1*sn) | ((u32)f2bf(x0*sn + x1*c) << 16);
}

// row softmax of scores/8, in place (bf16), row length 2048
__global__ void softmax_k(u16* __restrict__ sc)
{
  const long row = blockIdx.x;
  const int t = threadIdx.x;
  u16* p = sc + row*2048;
  const uint4 raw = ((const uint4*)p)[t];
  float v[8];
  v[0]=bf2f((u16)(raw.x&0xffffu)); v[1]=bf2f((u16)(raw.x>>16));
  v[2]=bf2f((u16)(raw.y&0xffffu)); v[3]=bf2f((u16)(raw.y>>16));
  v[4]=bf2f((u16)(raw.z&0xffffu)); v[5]=bf2f((u16)(raw.z>>16));
  v[6]=bf2f((u16)(raw.w&0xffffu)); v[7]=bf2f((u16)(raw.w>>16));
  float m = v[0];
  #pragma unroll
  for (int i=1;i<8;i++) m = fmaxf(m, v[i]);
  #pragma unroll
  for (int o=32;o>0;o>>=1) m = fmaxf(m, __shfl_down(m, o));
  __shared__ float redm[4], reds[4];
  if ((t&63)==0) redm[t>>6]=m;
  __syncthreads();
  m = fmaxf(fmaxf(redm[0],redm[1]), fmaxf(redm[2],redm[3]));
  float sum = 0.f;
  #pragma unroll
  for (int i=0;i<8;i++){ v[i] = expf((v[i]-m)*0.125f); sum += v[i]; }
  #pragma unroll
  for (int o=32;o>0;o>>=1) sum += __shfl_down(sum, o);
  if ((t&63)==0) reds[t>>6]=sum;
  __syncthreads();
  const float inv = 1.f/(reds[0]+reds[1]+reds[2]+reds[3]);
  uint4 o4;
  o4.x = (u32)f2bf(v[0]*inv) | ((u32)f2bf(v[1]*inv)<<16);
  o4.y = (u32)f2bf(v[2]*inv) | ((u32)f2bf(v[3]*inv)<<16);
  o4.z = (u32)f2bf(v[4]*inv) | ((u32)f2bf(v[5]*inv)<<16);
  o4.w = (u32)f2bf(v[6]*inv) | ((u32)f2bf(v[7]*inv)<<16);
  ((uint4*)p)[t] = o4;
}

// noisy top-2 router -> per-expert token lists (cnt/idx/gv)
__global__ void router_k(const float* __restrict__ h2, const float* __restrict__ wr,
                         const float* __restrict__ br, const float* __restrict__ wn,
                         const float* __restrict__ bn, const float* __restrict__ noise,
                         int* __restrict__ cnt, int* __restrict__ idxb,
                         float* __restrict__ gvb)
{
  const int tok = blockIdx.x, t = threadIdx.x;
  const float4 xv = ((const float4*)(h2 + (long)tok*D_))[t];
  const float xs[4] = {xv.x, xv.y, xv.z, xv.w};
  float ar[8], an[8];
  #pragma unroll
  for (int e=0;e<8;e++){ ar[e]=0.f; an[e]=0.f; }
  #pragma unroll
  for (int i=0;i<4;i++){
    const int d = t*4+i;
    const float* wrr = wr + d*8;
    const float* wnr = wn + d*8;
    #pragma unroll
    for (int e=0;e<8;e++){ ar[e] += xs[i]*wrr[e]; an[e] += xs[i]*wnr[e]; }
  }
  #pragma unroll
  for (int e=0;e<8;e++){
    #pragma unroll
    for (int o=32;o>0;o>>=1){ ar[e] += __shfl_down(ar[e], o); an[e] += __shfl_down(an[e], o); }
  }
  __shared__ float rr[4][8], rn[4][8];
  if ((t&63)==0){
    const int w4 = t>>6;
    #pragma unroll
    for (int e=0;e<8;e++){ rr[w4][e]=ar[e]; rn[w4][e]=an[e]; }
  }
  __syncthreads();
  if (t==0){
    float nz[8];
    #pragma unroll
    for (int e=0;e<8;e++){
      const float r  = rr[0][e]+rr[1][e]+rr[2][e]+rr[3][e] + br[e];
      const float ns = rn[0][e]+rn[1][e]+rn[2][e]+rn[3][e] + bn[e];
      const float sp = (ns > 20.f) ? ns : log1pf(expf(ns));
      nz[e] = r + noise[(long)tok*8+e]*sp;
    }
    int i0 = 0;
    #pragma unroll
    for (int e=1;e<8;e++) if (nz[e] > nz[i0]) i0 = e;
    int i1 = 0; float best = -3.0e38f;
    #pragma unroll
    for (int e=0;e<8;e++) if (e != i0 && nz[e] > best){ best = nz[e]; i1 = e; }
    const float e1  = expf(nz[i1]-nz[i0]);
    const float inv = 1.f/(1.f+e1);
    int p0 = atomicAdd(&cnt[i0], 1);
    idxb[i0*4096+p0] = tok; gvb[i0*4096+p0] = inv;
    int p1 = atomicAdd(&cnt[i1], 1);
    idxb[i1*4096+p1] = tok; gvb[i1*4096+p1] = e1*inv;
  }
}

__global__ void combine_k(const float* __restrict__ a, const float* __restrict__ b,
                          const float* __restrict__ c, float* __restrict__ o, long n4)
{
  long i = (long)blockIdx.x*blockDim.x + threadIdx.x;
  const long stride = (long)gridDim.x*blockDim.x;
  for (; i<n4; i+=stride){
    const float4 va = ((const float4*)a)[i];
    const float4 vb = ((const float4*)b)[i];
    const float4 vc = ((const float4*)c)[i];
    ((float4*)o)[i] = make_float4(va.x+vb.x+vc.x, va.y+vb.y+vc.y,
                                  va.z+vb.z+vc.z, va.w+vb.w+vc.w);
  }
}

// ---------------------------------------------------------------------------
extern "C" void kernel_launch(void* const* d_in, const int* in_sizes, int n_in,
                              void* d_out, int out_size, void* d_ws, size_t ws_size,
                              hipStream_t stream)
{
  const float* x      = (const float*)d_in[0];
  const float* fcos   = (const float*)d_in[1];
  const float* fsin   = (const float*)d_in[2];
  const float* rnoise = (const float*)d_in[3];
  const float* rms1w  = (const float*)d_in[4];
  const float* rms2w  = (const float*)d_in[5];
  const float* w_lq   = (const float*)d_in[6];
  const float* w_lkv  = (const float*)d_in[7];
  const float* w_q    = (const float*)d_in[8];
  const float* w_k    = (const float*)d_in[9];
  const float* w_v    = (const float*)d_in[10];
  const float* w_qr   = (const float*)d_in[11];
  const float* b_qr   = (const float*)d_in[12];
  const float* w_kr   = (const float*)d_in[13];
  const float* b_kr   = (const float*)d_in[14];
  const float* w_o    = (const float*)d_in[15];
  const float* b_o    = (const float*)d_in[16];
  const float* w_route= (const float*)d_in[17];
  const float* b_route= (const float*)d_in[18];
  const float* w_noise= (const float*)d_in[19];
  const float* b_noise= (const float*)d_in[20];
  const float* rW1    = (const float*)d_in[21];
  const float* rb1    = (const float*)d_in[22];
  const float* rW2    = (const float*)d_in[23];
  const float* rb2    = (const float*)d_in[24];
  const float* sW1    = (const float*)d_in[25];
  const float* sb1    = (const float*)d_in[26];
  const float* sW2    = (const float*)d_in[27];
  const float* sb2    = (const float*)d_in[28];

  if (ws_size < 165675136ULL) return;

  char* ws = (char*)d_ws;
  u16*   h_bf    = (u16*)(ws + 0);           // 8 MiB   (dead after kr GEMM)
  u16*   cq_bf   = (u16*)(ws + 8388608);     // 6 MiB
  u16*   ckv_bf  = (u16*)(ws + 14680064);    // 4 MiB
  u16*   v_bf    = (u16*)(ws + 18874368);    // 8 MiB   (dead after vt_k)
  u16*   qf      = (u16*)(ws + 27262976);    // 16 MiB  (dead after last QK)
  u16*   kf      = (u16*)(ws + 44040192);    // 16 MiB
  u16*   vt      = (u16*)(ws + 60817408);    // 8 MiB + 256 KiB pad
  u16*   attn_bf = (u16*)(ws + 69468160);    // 8 MiB
  float* x1      = (float*)(ws + 77856768);  // 16 MiB
  float* h2f     = (float*)(ws + 94633984);  // 16 MiB
  u16*   h2_bf   = (u16*)(ws + 111411200);   // 8 MiB
  float* facc    = (float*)(ws + 119799808); // 16 MiB
  int*   cnt     = (int*)(ws + 136577024);   // 32 B (pad 128)
  int*   idxb    = (int*)(ws + 136577152);   // 128 KiB
  float* gvb     = (float*)(ws + 136708224); // 128 KiB
  u16*   wlq_t   = (u16*)(ws + 136839296);
  u16*   wlkv_t  = (u16*)(ws + 138412160);
  u16*   wq_t    = (u16*)(ws + 139460736);
  u16*   wqr_t   = (u16*)(ws + 141033600);
  u16*   wk_t    = (u16*)(ws + 142606464);
  u16*   wkr_t   = (u16*)(ws + 143655040);
  u16*   wv_t    = (u16*)(ws + 145752192);
  u16*   wo_t    = (u16*)(ws + 146800768);   // 2 MiB (survives attention)
  u16*   W1t     = (u16*)(ws + 148897920);   // 8 MiB (expert phase)
  u16*   W2t     = (u16*)(ws + 157286528);   // 8 MiB -> end 165675136
  // temporal overlays:
  u16*   q_tmp   = (u16*)(ws + 77856768);    // pre-attention zone
  u16*   qr_tmp  = (u16*)(ws + 86245376);
  u16*   k_tmp   = (u16*)(ws + 94633984);
  u16*   kr_tmp  = (u16*)(ws + 103022592);
  u16*   scores  = (u16*)(ws + 77856768);    // 64 MiB during attention
  float* pvpart  = (float*)(ws + 148897920); // 8 MiB during attention (W1t/W2t slot)
  u16*   inter   = (u16*)(ws + 27262976);    // 32 MiB during experts (qf/kf slot)

  const dim3 blk(256,1,1);
  #define GEMM(FL,GRID,Aa,la,sa,Bb,lb,sb,Oo,lo,so,bi,re,gg,ii,cc,Kk,Nn) \
    gemm_k<FL><<<GRID, blk, 0, stream>>>(Aa,la,sa, Bb,lb,sb, (void*)(Oo),lo,so, bi,re,gg,ii,cc, Kk,Nn)

  // weight transposes (f32 [K][N] -> bf16 [N][K])
  tpose_k<<<dim3(24,32),blk,0,stream>>>(w_lq,  wlq_t, 1024, 768);
  tpose_k<<<dim3(16,32),blk,0,stream>>>(w_lkv, wlkv_t,1024, 512);
  tpose_k<<<dim3(32,24),blk,0,stream>>>(w_q,   wq_t,   768,1024);
  tpose_k<<<dim3(32,24),blk,0,stream>>>(w_qr,  wqr_t,  768,1024);
  tpose_k<<<dim3(32,16),blk,0,stream>>>(w_k,   wk_t,   512,1024);
  tpose_k<<<dim3(32,32),blk,0,stream>>>(w_kr,  wkr_t, 1024,1024);
  tpose_k<<<dim3(32,16),blk,0,stream>>>(w_v,   wv_t,   512,1024);
  tpose_k<<<dim3(32,32),blk,0,stream>>>(w_o,   wo_t,  1024,1024);

  rmsnorm_k<false><<<NTOK, blk, 0, stream>>>(x, rms1w, h_bf, nullptr);

  GEMM(F_OUTBF16, dim3(6,32,1),  h_bf,1024,0,  wlq_t,1024,0,  cq_bf,768,0,  nullptr,nullptr,nullptr,nullptr,nullptr, 1024, 768);
  GEMM(F_OUTBF16, dim3(4,32,1),  h_bf,1024,0,  wlkv_t,1024,0, ckv_bf,512,0, nullptr,nullptr,nullptr,nullptr,nullptr, 1024, 512);

  GEMM(F_OUTBF16,        dim3(8,32,1), cq_bf,768,0,  wq_t,768,0,   q_tmp,1024,0,  nullptr,nullptr,nullptr,nullptr,nullptr, 768, 1024);
  GEMM(F_OUTBF16|F_BIAS, dim3(8,32,1), cq_bf,768,0,  wqr_t,768,0,  qr_tmp,1024,0, b_qr,nullptr,nullptr,nullptr,nullptr,   768, 1024);
  GEMM(F_OUTBF16,        dim3(8,32,1), ckv_bf,512,0, wk_t,512,0,   k_tmp,1024,0,  nullptr,nullptr,nullptr,nullptr,nullptr, 512, 1024);
  GEMM(F_OUTBF16|F_BIAS, dim3(8,32,1), h_bf,1024,0,  wkr_t,1024,0, kr_tmp,1024,0, b_kr,nullptr,nullptr,nullptr,nullptr,  1024, 1024);
  GEMM(F_OUTBF16,        dim3(8,32,1), ckv_bf,512,0, wv_t,512,0,   v_bf,1024,0,   nullptr,nullptr,nullptr,nullptr,nullptr, 512, 1024);

  rope_concat_k<<<8192, blk, 0, stream>>>(q_tmp, qr_tmp, k_tmp, kr_tmp, fcos, fsin, qf, kf);
  vt_k<<<dim3(64,2,32), blk, 0, stream>>>(v_bf, vt);

  // attention: 4 chunks of 8 heads; scores = 64 MiB; PV split-K x2 (256 blocks)
  for (int c=0;c<4;c++){
    const int b = c >> 1, h0 = (c & 1) * 8;
    const u16* qfs = qf + (long)b*4194304 + h0*128;
    const u16* kfs = kf + (long)b*4194304 + h0*128;
    GEMM(F_OUTBF16, dim3(16,16,8), qfs,2048,128, kfs,2048,128, scores,2048,4194304L,
         nullptr,nullptr,nullptr,nullptr,nullptr, 128, 2048);
    softmax_k<<<16384, blk, 0, stream>>>(scores);
    const u16* vs = vt + (long)(b*16 + h0)*131072;
    GEMM(F_PVOUT, dim3(1,16,16), scores,2048,4194304L, vs,2048,131072L, pvpart,512,1048576L,
         nullptr,nullptr,nullptr,nullptr,nullptr, 1024, 64);
    pvcomb_k<<<2048, blk, 0, stream>>>(pvpart, attn_bf + (long)b*2097152 + h0*64);
  }

  // x1 = x + attn@w_o + b_o ; h2 = rmsnorm(x1)
  GEMM(F_BIAS|F_RESID, dim3(8,32,1), attn_bf,1024,0, wo_t,1024,0, x1,1024,0,
       b_o, x, nullptr,nullptr,nullptr, 1024, 1024);
  rmsnorm_k<true><<<NTOK, blk, 0, stream>>>(x1, rms2w, h2_bf, h2f);

  // router -> per-expert lists
  hipMemsetAsync(cnt, 0, 128, stream);
  router_k<<<NTOK, blk, 0, stream>>>(h2f, w_route, b_route, w_noise, b_noise, rnoise,
                                     cnt, idxb, gvb);
  hipMemsetAsync(facc, 0, 16777216, stream);

  // routed experts: sparse gather/scatter (worst-case grids, early-exit on cnt)
  for (int e=0;e<8;e++){
    tpose_k<<<dim3(128,32),blk,0,stream>>>(rW1 + (long)e*4194304, W1t, 1024, 4096);
    tpose_k<<<dim3(32,128),blk,0,stream>>>(rW2 + (long)e*4194304, W2t, 4096, 1024);
    GEMM(F_OUTBF16|F_BIAS|F_RELU|F_GATHER, dim3(32,32,1), h2_bf,1024,0, W1t,1024,0,
         inter,4096,0, rb1 + e*4096, nullptr, nullptr, idxb + e*4096, cnt + e, 1024, 4096);
    GEMM(F_BIAS|F_SCATTER, dim3(8,32,1), inter,4096,0, W2t,4096,0, facc,1024,0,
         rb2 + e*1024, nullptr, gvb + e*4096, idxb + e*4096, cnt + e, 4096, 1024);
  }
  // shared experts: dense, += facc
  for (int j=0;j<2;j++){
    tpose_k<<<dim3(128,32),blk,0,stream>>>(sW1 + (long)j*4194304, W1t, 1024, 4096);
    tpose_k<<<dim3(32,128),blk,0,stream>>>(sW2 + (long)j*4194304, W2t, 4096, 1024);
    GEMM(F_OUTBF16|F_BIAS|F_RELU, dim3(32,32,1), h2_bf,1024,0, W1t,1024,0, inter,4096,0,
         sb1 + j*4096, nullptr,nullptr,nullptr,nullptr, 1024, 4096);
    GEMM(F_BIAS|F_GATEACC, dim3(8,32,1), inter,4096,0, W2t,4096,0, facc,1024,0,
         sb2 + j*1024, nullptr,nullptr,nullptr,nullptr, 4096, 1024);
  }

  combine_k<<<2048, blk, 0, stream>>>(x1, h2f, facc, (float*)d_out, 1048576L);
}

// Round 6
// 1571.049 us; speedup vs baseline: 1.4701x; 1.4701x over previous
//
#include <hip/hip_runtime.h>
#include <cstdint>

typedef unsigned short u16;
typedef unsigned int   u32;
using short8 = __attribute__((ext_vector_type(8))) short;
using f32x4  = __attribute__((ext_vector_type(4))) float;

#define S_   2048
#define D_   1024
#define NTOK 4096   /* B*S */

__device__ __forceinline__ u16 f2bf(float f){
  u32 u = __float_as_uint(f);
  u32 r = u + 0x7fffu + ((u >> 16) & 1u);   // RNE
  return (u16)(r >> 16);
}
__device__ __forceinline__ float bf2f(u16 h){
  return __uint_as_float(((u32)h) << 16);
}
__device__ __forceinline__ void gld16(const void* g, void* l){
  __builtin_amdgcn_global_load_lds((__attribute__((address_space(1))) void*)(void*)g,
                                   (__attribute__((address_space(3))) void*)l, 16, 0, 0);
}

// ---------------------------------------------------------------------------
// bf16 MFMA GEMM (NT): C[M,N] = A[M,K] * Bt[N,K]^T, 128x128x32 tiles, 4 waves.
// F_GATHER : A rows gathered via idx list (expert e=ebase+z, list at off[e]);
//            output rows packed at off[e]+row in `out`.
// F_SCATTER: A rows at off[e]+row of inter; output row -> token via idx;
//            slot 0 -> out (f32, '='), slot 1 -> out2 (f32, '=').
// F_EXPB   : bias indexed per expert: bias + (ebase+z)*ncols.
// F_PVOUT  : z = ks*8+hl; f32 partials [ks][row][hl*64+col].
// XCD-aware bijective block swizzle (m204).
// ---------------------------------------------------------------------------
enum { F_OUTBF16=1, F_BIAS=2, F_RELU=4, F_RESID=8, F_GATEACC=16,
       F_GATHER=64, F_SCATTER=128, F_PVOUT=256, F_EXPB=512 };

template<int FLAGS>
__global__ void __launch_bounds__(256, 4)
gemm_k(const u16* __restrict__ A, int lda, long sAz,
       const u16* __restrict__ Bt, int ldb, long sBz,
       void* __restrict__ out, int ldo, long sOz,
       float* __restrict__ out2,
       const float* __restrict__ bias,
       const float* __restrict__ resid,
       const float* __restrict__ gv,
       const int* __restrict__ idx,
       const int* __restrict__ slotb,
       const int* __restrict__ cntp, int ebase,
       int K, int ncols)
{
  constexpr int BM = 128, BK = 32;
  const int tid = threadIdx.x;
  const int w = tid >> 6, l = tid & 63;
  const int wr = w >> 1, wc = w & 1;

  // bijective XCD swizzle
  const int gx = gridDim.x, gy = gridDim.y;
  const int nwg = gx*gy*gridDim.z;
  const int flat = (blockIdx.z*gy + blockIdx.y)*gx + blockIdx.x;
  const int q8 = nwg >> 3, r8 = nwg & 7, xcd = flat & 7, off8 = flat >> 3;
  const int swz = (xcd < r8) ? (xcd*(q8+1) + off8)
                             : (r8*(q8+1) + (xcd-r8)*q8 + off8);
  const int tn = swz % gx;
  const int rest = swz / gx;
  const int tm = rest % gy;
  const int z  = rest / gy;
  const int ncol0 = tn * 128;

  int cnt = 0x7fffffff; long ofs = 0;
  if constexpr (FLAGS & (F_GATHER|F_SCATTER)){
    const int e = ebase + z;
    cnt = cntp[e]; ofs = (long)cntp[8+e];
    if (tm*BM >= cnt) return;
  }

  const u16 *Abase, *Btbase;
  if constexpr (FLAGS & F_PVOUT){
    Abase  = A  + (long)(z&7)*sAz + (long)(z>>3)*K + (long)tm*BM*lda;
    Btbase = Bt + (long)(z&7)*sBz + (long)(z>>3)*K + (long)ncol0*ldb;
  } else if constexpr (FLAGS & F_GATHER){
    Abase  = A;                              // rows via idx
    Btbase = Bt + (long)z*sBz + (long)ncol0*ldb;
  } else if constexpr (FLAGS & F_SCATTER){
    Abase  = A + ofs*lda + (long)tm*BM*lda;
    Btbase = Bt + (long)z*sBz + (long)ncol0*ldb;
  } else {
    Abase  = A  + (long)z*sAz + (long)tm*BM*lda;
    Btbase = Bt + (long)z*sBz + (long)ncol0*ldb;
  }

  const int r0 = tid >> 2, seg = tid & 3;
  long aoff0, aoff1;
  if constexpr (FLAGS & F_GATHER){
    const int p0 = tm*BM + r0, p1 = p0 + 64;
    const int t0 = (p0 < cnt) ? idx[ofs + p0] : 0;
    const int t1 = (p1 < cnt) ? idx[ofs + p1] : 0;
    aoff0 = (long)t0*lda; aoff1 = (long)t1*lda;
  } else {
    aoff0 = (long)r0*lda; aoff1 = (long)(r0+64)*lda;
  }
  const u16* pA0 = Abase + aoff0 + seg*8;
  const u16* pA1 = Abase + aoff1 + seg*8;
  const u16* pB0 = Btbase + (long)r0*ldb + seg*8;
  const u16* pB1 = Btbase + (long)(r0+64)*ldb + seg*8;

  __shared__ __align__(16) u16 As[2][BM*BK];
  __shared__ __align__(16) u16 Bs[2][BM*BK];

  f32x4 zero = {0.f,0.f,0.f,0.f};
  f32x4 acc[4][4];
  #pragma unroll
  for (int i=0;i<4;i++)
    #pragma unroll
    for (int j=0;j<4;j++) acc[i][j] = zero;

  const int NK = K >> 5;

  auto stage = [&](int buf, int kt){
    const int k0 = kt*BK;
    gld16(pA0 + k0, &As[buf][(w*64)*8]);
    gld16(pA1 + k0, &As[buf][(256 + w*64)*8]);
    gld16(pB0 + k0, &Bs[buf][(w*64)*8]);
    gld16(pB1 + k0, &Bs[buf][(256 + w*64)*8]);
  };

  stage(0,0);
  __syncthreads();

  for (int kt=0; kt<NK; ++kt){
    const int cur = kt & 1, nxt = cur ^ 1;
    if (kt+1 < NK) stage(nxt, kt+1);
    short8 a[4], b[4];
    #pragma unroll
    for (int m=0;m<4;m++){
      const int arow = wr*64 + m*16 + (l & 15);
      a[m] = *(const short8*)&As[cur][arow*BK + (l>>4)*8];
    }
    #pragma unroll
    for (int n=0;n<4;n++){
      const int brow = wc*64 + n*16 + (l & 15);
      b[n] = *(const short8*)&Bs[cur][brow*BK + (l>>4)*8];
    }
    #pragma unroll
    for (int m=0;m<4;m++)
      #pragma unroll
      for (int n=0;n<4;n++)
        acc[m][n] = __builtin_amdgcn_mfma_f32_16x16x32_bf16(a[m], b[n], acc[m][n], 0, 0, 0);
    __syncthreads();
  }

  // epilogue  (C/D: col = lane&15, row = (lane>>4)*4 + reg)
  float* outf = (float*)out + (long)z*sOz;
  u16*   outh = (u16*)out + (long)z*sOz;
  float* pvf  = (float*)out + (long)(z>>3)*sOz;   // PVOUT
  const float* bp = bias;
  if constexpr (FLAGS & F_EXPB) bp += (long)(ebase+z)*ncols;
  const long row0 = (long)tm*BM + wr*64;
  #pragma unroll
  for (int m=0;m<4;m++){
    #pragma unroll
    for (int n=0;n<4;n++){
      const int col = ncol0 + wc*64 + n*16 + (l & 15);
      if (col < ncols){
        #pragma unroll
        for (int r=0;r<4;r++){
          const long row = row0 + m*16 + ((l>>4)*4) + r;
          float v = acc[m][n][r];
          if constexpr (FLAGS & F_BIAS) v += bp[col];
          if constexpr (FLAGS & F_RELU) v = fmaxf(v, 0.f);
          if constexpr (FLAGS & F_PVOUT){
            pvf[row*(long)ldo + (z&7)*64 + col] = v;
          } else if constexpr (FLAGS & F_SCATTER){
            if (row < cnt){
              const long gs = ofs + row;
              const int tok = idx[gs];
              float* dst = slotb[gs] ? out2 : (float*)out;
              dst[(long)tok*ldo + col] = gv[gs] * v;
            }
          } else if constexpr (FLAGS & F_GATHER){
            if (row < cnt) outh[(ofs + row)*(long)ldo + col] = f2bf(v);
          } else if constexpr (FLAGS & F_GATEACC){
            outf[row*(long)ldo + col] += v;
          } else if constexpr (FLAGS & F_RESID){
            const long off = row*(long)ldo + col;
            outf[off] = resid[off] + v;
          } else if constexpr (FLAGS & F_OUTBF16){
            outh[row*(long)ldo + col] = f2bf(v);
          } else {
            outf[row*(long)ldo + col] = v;
          }
        }
      }
    }
  }
}

// ---------------------------------------------------------------------------
// batched transpose f32 [K][N] (ld=N) -> bf16 [N][K] (ld=K); z via strides.
__global__ void tpose_k(const float* __restrict__ src, u16* __restrict__ dst,
                        int K, int N, long szS, long szD)
{
  __shared__ u16 tile[32][36];
  const int t = threadIdx.x;
  src += (long)blockIdx.z*szS; dst += (long)blockIdx.z*szD;
  const int n0 = blockIdx.x*32, k0 = blockIdx.y*32;
  const int lr = t >> 3, lc = (t & 7) * 4;
  const float4 v = *(const float4*)&src[(long)(k0+lr)*N + n0 + lc];
  ushort4 tv; tv.x=f2bf(v.x); tv.y=f2bf(v.y); tv.z=f2bf(v.z); tv.w=f2bf(v.w);
  *(ushort4*)&tile[lr][lc] = tv;
  __syncthreads();
  ushort4 o;
  o.x = tile[lc+0][lr]; o.y = tile[lc+1][lr];
  o.z = tile[lc+2][lr]; o.w = tile[lc+3][lr];
  *(ushort4*)&dst[(long)(n0+lr)*K + k0 + lc] = o;
}

// v_bf [b][s][h*64+d] -> vt [(b*16+h)][d][s]
__global__ void vt_k(const u16* __restrict__ src, u16* __restrict__ dst)
{
  __shared__ u16 tile[32][36];
  const int t = threadIdx.x;
  const int z = blockIdx.z;            // b*16+h
  const int b = z >> 4, h = z & 15;
  const int s0 = blockIdx.x*32, d0 = blockIdx.y*32;
  const int lr = t >> 3, lc = (t & 7) * 4;
  ushort4 v = *(const ushort4*)&src[(long)(b*2048 + s0+lr)*1024 + h*64 + d0 + lc];
  *(ushort4*)&tile[lr][lc] = v;
  __syncthreads();
  ushort4 o;
  o.x = tile[lc+0][lr]; o.y = tile[lc+1][lr];
  o.z = tile[lc+2][lr]; o.w = tile[lc+3][lr];
  *(ushort4*)&dst[(long)z*131072 + (long)(d0+lr)*2048 + s0 + lc] = o;
}

// sum two f32 PV partials -> bf16 attn rows
__global__ void pvcomb_k(const float* __restrict__ p, u16* __restrict__ dst)
{
  const int row = blockIdx.x, t = threadIdx.x;
  const float2 v0 = ((const float2*)(p + (long)row*512))[t];
  const float2 v1 = ((const float2*)(p + 1048576 + (long)row*512))[t];
  u32 pk = (u32)f2bf(v0.x+v1.x) | ((u32)f2bf(v0.y+v1.y) << 16);
  *(u32*)&dst[(long)row*1024 + t*2] = pk;
}

// ---------------------------------------------------------------------------
template<bool WF32>
__global__ void rmsnorm_k(const float* __restrict__ x, const float* __restrict__ w,
                          u16* __restrict__ ob, float* __restrict__ of)
{
  const int row = blockIdx.x, t = threadIdx.x;
  const float4 v = ((const float4*)(x + (long)row*D_))[t];
  float ss = v.x*v.x + v.y*v.y + v.z*v.z + v.w*v.w;
  #pragma unroll
  for (int o=32;o>0;o>>=1) ss += __shfl_down(ss, o);
  __shared__ float red[4];
  if ((t&63)==0) red[t>>6] = ss;
  __syncthreads();
  const float scale = rsqrtf((red[0]+red[1]+red[2]+red[3])*(1.0f/D_) + 1e-6f);
  const float4 wv = ((const float4*)w)[t];
  const float o0=v.x*scale*wv.x, o1=v.y*scale*wv.y, o2=v.z*scale*wv.z, o3=v.w*scale*wv.w;
  const long base = (long)row*D_ + t*4;
  uint2 p; p.x = (u32)f2bf(o0) | ((u32)f2bf(o1)<<16);
  p.y = (u32)f2bf(o2) | ((u32)f2bf(o3)<<16);
  *(uint2*)&ob[base] = p;
  if constexpr (WF32) *(float4*)&of[base] = make_float4(o0,o1,o2,o3);
}

// qf = [q | rope(qr)], kf = [k | rope(kr)]
__global__ void rope_concat_k(const u16* __restrict__ qt, const u16* __restrict__ qrt,
                              const u16* __restrict__ kt, const u16* __restrict__ krt,
                              const float* __restrict__ fc, const float* __restrict__ fs,
                              u16* __restrict__ qf, u16* __restrict__ kf)
{
  const int idx = blockIdx.x*256 + threadIdx.x;
  const int j = idx & 31, h = (idx>>5) & 15, bs = idx >> 9;
  if (bs >= NTOK) return;
  const int s = bs & (S_-1);
  const float c = fc[s*32+j], sn = fs[s*32+j];
  const long ib = (long)bs*1024 + h*64 + 2*j;
  const long ob = (long)bs*2048 + h*128 + 2*j;
  *(u32*)&qf[ob] = *(const u32*)&qt[ib];
  *(u32*)&kf[ob] = *(const u32*)&kt[ib];
  float x0 = bf2f(qrt[ib]), x1 = bf2f(qrt[ib+1]);
  *(u32*)&qf[ob+64] = (u32)f2bf(x0*c - x1*sn) | ((u32)f2bf(x0*sn + x1*c) << 16);
  x0 = bf2f(krt[ib]); x1 = bf2f(krt[ib+1]);
  *(u32*)&kf[ob+64] = (u32)f2bf(x0*c - x1*sn) | ((u32)f2bf(x0*sn + x1*c) << 16);
}

// row softmax of scores/8, in place (bf16), row length 2048
__global__ void softmax_k(u16* __restrict__ sc)
{
  const long row = blockIdx.x;
  const int t = threadIdx.x;
  u16* p = sc + row*2048;
  const uint4 raw = ((const uint4*)p)[t];
  float v[8];
  v[0]=bf2f((u16)(raw.x&0xffffu)); v[1]=bf2f((u16)(raw.x>>16));
  v[2]=bf2f((u16)(raw.y&0xffffu)); v[3]=bf2f((u16)(raw.y>>16));
  v[4]=bf2f((u16)(raw.z&0xffffu)); v[5]=bf2f((u16)(raw.z>>16));
  v[6]=bf2f((u16)(raw.w&0xffffu)); v[7]=bf2f((u16)(raw.w>>16));
  float m = v[0];
  #pragma unroll
  for (int i=1;i<8;i++) m = fmaxf(m, v[i]);
  #pragma unroll
  for (int o=32;o>0;o>>=1) m = fmaxf(m, __shfl_down(m, o));
  __shared__ float redm[4], reds[4];
  if ((t&63)==0) redm[t>>6]=m;
  __syncthreads();
  m = fmaxf(fmaxf(redm[0],redm[1]), fmaxf(redm[2],redm[3]));
  float sum = 0.f;
  #pragma unroll
  for (int i=0;i<8;i++){ v[i] = expf((v[i]-m)*0.125f); sum += v[i]; }
  #pragma unroll
  for (int o=32;o>0;o>>=1) sum += __shfl_down(sum, o);
  if ((t&63)==0) reds[t>>6]=sum;
  __syncthreads();
  const float inv = 1.f/(reds[0]+reds[1]+reds[2]+reds[3]);
  uint4 o4;
  o4.x = (u32)f2bf(v[0]*inv) | ((u32)f2bf(v[1]*inv)<<16);
  o4.y = (u32)f2bf(v[2]*inv) | ((u32)f2bf(v[3]*inv)<<16);
  o4.z = (u32)f2bf(v[4]*inv) | ((u32)f2bf(v[5]*inv)<<16);
  o4.w = (u32)f2bf(v[6]*inv) | ((u32)f2bf(v[7]*inv)<<16);
  ((uint4*)p)[t] = o4;
}

// noisy top-2 per token -> eids (i0|i1<<8), gates (g0,g1).  Deterministic.
__global__ void topk_k(const float* __restrict__ h2, const float* __restrict__ wr,
                       const float* __restrict__ br, const float* __restrict__ wn,
                       const float* __restrict__ bn, const float* __restrict__ noise,
                       int* __restrict__ eids, float2* __restrict__ gates)
{
  const int tok = blockIdx.x, t = threadIdx.x;
  const float4 xv = ((const float4*)(h2 + (long)tok*D_))[t];
  const float xs[4] = {xv.x, xv.y, xv.z, xv.w};
  float ar[8], an[8];
  #pragma unroll
  for (int e=0;e<8;e++){ ar[e]=0.f; an[e]=0.f; }
  #pragma unroll
  for (int i=0;i<4;i++){
    const int d = t*4+i;
    const float* wrr = wr + d*8;
    const float* wnr = wn + d*8;
    #pragma unroll
    for (int e=0;e<8;e++){ ar[e] += xs[i]*wrr[e]; an[e] += xs[i]*wnr[e]; }
  }
  #pragma unroll
  for (int e=0;e<8;e++){
    #pragma unroll
    for (int o=32;o>0;o>>=1){ ar[e] += __shfl_down(ar[e], o); an[e] += __shfl_down(an[e], o); }
  }
  __shared__ float rr[4][8], rn[4][8];
  if ((t&63)==0){
    const int w4 = t>>6;
    #pragma unroll
    for (int e=0;e<8;e++){ rr[w4][e]=ar[e]; rn[w4][e]=an[e]; }
  }
  __syncthreads();
  if (t==0){
    float nz[8];
    #pragma unroll
    for (int e=0;e<8;e++){
      const float r  = rr[0][e]+rr[1][e]+rr[2][e]+rr[3][e] + br[e];
      const float ns = rn[0][e]+rn[1][e]+rn[2][e]+rn[3][e] + bn[e];
      const float sp = (ns > 20.f) ? ns : log1pf(expf(ns));
      nz[e] = r + noise[(long)tok*8+e]*sp;
    }
    int i0 = 0;
    #pragma unroll
    for (int e=1;e<8;e++) if (nz[e] > nz[i0]) i0 = e;
    int i1 = -1; float best = -3.0e38f;
    #pragma unroll
    for (int e=0;e<8;e++) if (e != i0 && nz[e] > best){ best = nz[e]; i1 = e; }
    const float e1  = expf(nz[i1]-nz[i0]);
    const float inv = 1.f/(1.f+e1);
    eids[tok] = i0 | (i1 << 8);
    gates[tok] = make_float2(inv, e1*inv);
  }
}

// build token-ordered per-expert lists.  SINGLE WAVE (64 thr), barrier-free.
__global__ void __launch_bounds__(64)
compact_k(const int* __restrict__ eids, const float2* __restrict__ gates,
          int* __restrict__ cntoff, int* __restrict__ idxb,
          float* __restrict__ gvb, int* __restrict__ slotb)
{
  const int t = threadIdx.x;   // 0..63, each owns tokens [t*64, t*64+64)
  int base = 0;
  for (int e=0;e<8;e++){
    int c = 0;
    for (int i=0;i<64;i++){
      const int id = eids[t*64+i];
      const int i0 = id & 255, i1 = (id >> 8) & 255;
      c += (i0==e || i1==e) ? 1 : 0;
    }
    int sc = c;                         // inclusive scan over the wave
    #pragma unroll
    for (int o=1;o<64;o<<=1){ int u = __shfl_up(sc, o); if (t >= o) sc += u; }
    const int tot = __shfl(sc, 63);
    int pos = base + (sc - c);          // exclusive prefix
    for (int i=0;i<64;i++){
      const int tok = t*64+i;
      const int id = eids[tok];
      const int i0 = id & 255, i1 = (id >> 8) & 255;
      if (i0==e || i1==e){
        const float2 g = gates[tok];
        idxb[pos]  = tok;
        gvb[pos]   = (i0==e) ? g.x : g.y;
        slotb[pos] = (i0==e) ? 0 : 1;
        pos++;
      }
    }
    if (t==0){ cntoff[e] = tot; cntoff[8+e] = base; }
    base += tot;
  }
}

// o = a + b
__global__ void addstore_k(const float* __restrict__ a, const float* __restrict__ b,
                           float* __restrict__ o, long n4)
{
  long i = (long)blockIdx.x*blockDim.x + threadIdx.x;
  const long stride = (long)gridDim.x*blockDim.x;
  for (; i<n4; i+=stride){
    const float4 va = ((const float4*)a)[i];
    const float4 vb = ((const float4*)b)[i];
    ((float4*)o)[i] = make_float4(va.x+vb.x, va.y+vb.y, va.z+vb.z, va.w+vb.w);
  }
}
// o += a + b
__global__ void addacc_k(const float* __restrict__ a, const float* __restrict__ b,
                         float* __restrict__ o, long n4)
{
  long i = (long)blockIdx.x*blockDim.x + threadIdx.x;
  const long stride = (long)gridDim.x*blockDim.x;
  for (; i<n4; i+=stride){
    const float4 va = ((const float4*)a)[i];
    const float4 vb = ((const float4*)b)[i];
    float4 vo = ((const float4*)o)[i];
    ((float4*)o)[i] = make_float4(vo.x+va.x+vb.x, vo.y+va.y+vb.y,
                                  vo.z+va.z+vb.z, vo.w+va.w+vb.w);
  }
}

// ---------------------------------------------------------------------------
extern "C" void kernel_launch(void* const* d_in, const int* in_sizes, int n_in,
                              void* d_out, int out_size, void* d_ws, size_t ws_size,
                              hipStream_t stream)
{
  const float* x      = (const float*)d_in[0];
  const float* fcos   = (const float*)d_in[1];
  const float* fsin   = (const float*)d_in[2];
  const float* rnoise = (const float*)d_in[3];
  const float* rms1w  = (const float*)d_in[4];
  const float* rms2w  = (const float*)d_in[5];
  const float* w_lq   = (const float*)d_in[6];
  const float* w_lkv  = (const float*)d_in[7];
  const float* w_q    = (const float*)d_in[8];
  const float* w_k    = (const float*)d_in[9];
  const float* w_v    = (const float*)d_in[10];
  const float* w_qr   = (const float*)d_in[11];
  const float* b_qr   = (const float*)d_in[12];
  const float* w_kr   = (const float*)d_in[13];
  const float* b_kr   = (const float*)d_in[14];
  const float* w_o    = (const float*)d_in[15];
  const float* b_o    = (const float*)d_in[16];
  const float* w_route= (const float*)d_in[17];
  const float* b_route= (const float*)d_in[18];
  const float* w_noise= (const float*)d_in[19];
  const float* b_noise= (const float*)d_in[20];
  const float* rW1    = (const float*)d_in[21];
  const float* rb1    = (const float*)d_in[22];
  const float* rW2    = (const float*)d_in[23];
  const float* rb2    = (const float*)d_in[24];
  const float* sW1    = (const float*)d_in[25];
  const float* sb1    = (const float*)d_in[26];
  const float* sW2    = (const float*)d_in[27];
  const float* sb2    = (const float*)d_in[28];

  if (ws_size < 195166208ULL) return;

  char* ws = (char*)d_ws;
  // persistent / phased buffers
  u16*   h_bf    = (u16*)(ws + 0);           // P1
  u16*   cq_bf   = (u16*)(ws + 8388608);     // P1
  u16*   ckv_bf  = (u16*)(ws + 14680064);    // P1
  u16*   v_bf    = (u16*)(ws + 18874368);    // P1
  u16*   qf      = (u16*)(ws + 27262976);    // P1-P2, 16 MiB
  u16*   kf      = (u16*)(ws + 44040192);    // P1-P2, 16 MiB
  u16*   vt      = (u16*)(ws + 60817408);    // P1-P2, 8.25 MiB -> 69468160
  u16*   attn_bf = (u16*)(ws + 69468160);    // P2-P3, 8 MiB
  float* x1      = (float*)(ws + 77856768);  // P3-P4, 16 MiB
  float* h2f     = (float*)(ws + 94633984);  // P3-P4, 16 MiB
  u16*   h2_bf   = (u16*)(ws + 111411200);   // P3-P4, 8 MiB
  float* faccA   = (float*)(ws + 119799808); // P4, 16 MiB (slot0 scatter)
  float* faccB   = (float*)(ws + 136577024); // P4, 16 MiB (slot1 scatter)
  u16*   Wt_g    = (u16*)(ws + 153354240);   // P4, 32 MiB -> ends 186908672
  int*   cntoff  = (int*)(ws + 189005824);   // 16 ints
  int*   eids    = (int*)(ws + 189006080);
  float2* gatesb = (float2*)(ws + 189022464);
  int*   idxb    = (int*)(ws + 189055232);
  float* gvb     = (float*)(ws + 189088000);
  int*   slotb   = (int*)(ws + 189120768);   // ends 189153536
  u16*   wo_t    = (u16*)(ws + 189153536);   // 2 MiB, NO overlap w/ Wt_g now
  // temporal overlays
  u16*   q_tmp   = (u16*)(ws + 77856768);    // P1
  u16*   qr_tmp  = (u16*)(ws + 86245376);
  u16*   k_tmp   = (u16*)(ws + 94633984);
  u16*   kr_tmp  = (u16*)(ws + 103022592);
  u16*   scores  = (u16*)(ws + 77856768);    // P2, 64 MiB
  float* pvpart  = (float*)(ws + 146538496); // P2, 8 MiB
  u16*   inter   = (u16*)(ws + 0);           // P4, 64 MiB (8192 x 4096 bf16)
  // small weight transposes (P1 zone, overlaid on faccA region)
  u16*   wlq_t   = (u16*)(ws + 119799808);
  u16*   wlkv_t  = (u16*)(ws + 121372672);
  u16*   wq_t    = (u16*)(ws + 122421248);
  u16*   wqr_t   = (u16*)(ws + 123994112);
  u16*   wk_t    = (u16*)(ws + 125566976);
  u16*   wkr_t   = (u16*)(ws + 126615552);
  u16*   wv_t    = (u16*)(ws + 128712704);

  const dim3 blk(256,1,1);
  #define GEMM(FL, GRID, ...) gemm_k<FL><<<GRID, blk, 0, stream>>>(__VA_ARGS__)
  #define NOSPARSE nullptr,nullptr,nullptr,nullptr,nullptr,nullptr,nullptr,0

  // P0: small weight transposes (f32 [K][N] -> bf16 [N][K])
  tpose_k<<<dim3(24,32),blk,0,stream>>>(w_lq,  wlq_t, 1024, 768, 0,0);
  tpose_k<<<dim3(16,32),blk,0,stream>>>(w_lkv, wlkv_t,1024, 512, 0,0);
  tpose_k<<<dim3(32,24),blk,0,stream>>>(w_q,   wq_t,   768,1024, 0,0);
  tpose_k<<<dim3(32,24),blk,0,stream>>>(w_qr,  wqr_t,  768,1024, 0,0);
  tpose_k<<<dim3(32,16),blk,0,stream>>>(w_k,   wk_t,   512,1024, 0,0);
  tpose_k<<<dim3(32,32),blk,0,stream>>>(w_kr,  wkr_t, 1024,1024, 0,0);
  tpose_k<<<dim3(32,16),blk,0,stream>>>(w_v,   wv_t,   512,1024, 0,0);
  tpose_k<<<dim3(32,32),blk,0,stream>>>(w_o,   wo_t,  1024,1024, 0,0);

  // P1: rmsnorm + projections + rope
  rmsnorm_k<false><<<NTOK, blk, 0, stream>>>(x, rms1w, h_bf, nullptr);

  GEMM(F_OUTBF16, dim3(6,32,1),  h_bf,1024,0,  wlq_t,1024,0,  cq_bf,768,0,  NOSPARSE, 1024, 768);
  GEMM(F_OUTBF16, dim3(4,32,1),  h_bf,1024,0,  wlkv_t,1024,0, ckv_bf,512,0, NOSPARSE, 1024, 512);
  GEMM(F_OUTBF16, dim3(8,32,1),  cq_bf,768,0,  wq_t,768,0,    q_tmp,1024,0, NOSPARSE, 768, 1024);
  GEMM(F_OUTBF16|F_BIAS, dim3(8,32,1), cq_bf,768,0, wqr_t,768,0, qr_tmp,1024,0,
       nullptr, b_qr, nullptr,nullptr,nullptr,nullptr,nullptr,0, 768, 1024);
  GEMM(F_OUTBF16, dim3(8,32,1),  ckv_bf,512,0, wk_t,512,0,    k_tmp,1024,0, NOSPARSE, 512, 1024);
  GEMM(F_OUTBF16|F_BIAS, dim3(8,32,1), h_bf,1024,0, wkr_t,1024,0, kr_tmp,1024,0,
       nullptr, b_kr, nullptr,nullptr,nullptr,nullptr,nullptr,0, 1024, 1024);
  GEMM(F_OUTBF16, dim3(8,32,1),  ckv_bf,512,0, wv_t,512,0,    v_bf,1024,0,  NOSPARSE, 512, 1024);

  rope_concat_k<<<8192, blk, 0, stream>>>(q_tmp, qr_tmp, k_tmp, kr_tmp, fcos, fsin, qf, kf);
  vt_k<<<dim3(64,2,32), blk, 0, stream>>>(v_bf, vt);

  // P2: attention, 4 chunks of 8 heads; PV split-K x2 (256 blocks)
  for (int c=0;c<4;c++){
    const int b = c >> 1, h0 = (c & 1) * 8;
    const u16* qfs = qf + (long)b*4194304 + h0*128;
    const u16* kfs = kf + (long)b*4194304 + h0*128;
    GEMM(F_OUTBF16, dim3(16,16,8), qfs,2048,128, kfs,2048,128, scores,2048,4194304L,
         NOSPARSE, 128, 2048);
    softmax_k<<<16384, blk, 0, stream>>>(scores);
    const u16* vs = vt + (long)(b*16 + h0)*131072;
    GEMM(F_PVOUT, dim3(1,16,16), scores,2048,4194304L, vs,2048,131072L, pvpart,512,1048576L,
         NOSPARSE, 1024, 64);
    pvcomb_k<<<2048, blk, 0, stream>>>(pvpart, attn_bf + (long)b*2097152 + h0*64);
  }

  // P3: o-proj + rmsnorm2 + router
  GEMM(F_BIAS|F_RESID, dim3(8,32,1), attn_bf,1024,0, wo_t,1024,0, x1,1024,0,
       nullptr, b_o, x, nullptr,nullptr,nullptr,nullptr,0, 1024, 1024);
  rmsnorm_k<true><<<NTOK, blk, 0, stream>>>(x1, rms2w, h2_bf, h2f);
  topk_k<<<NTOK, blk, 0, stream>>>(h2f, w_route, b_route, w_noise, b_noise, rnoise,
                                   eids, gatesb);
  compact_k<<<1, 64, 0, stream>>>(eids, gatesb, cntoff, idxb, gvb, slotb);
  addstore_k<<<2048, blk, 0, stream>>>(x1, h2f, (float*)d_out, 1048576L);  // out = x1+h2
  hipMemsetAsync(faccA, 0, 33554432, stream);  // zero faccA+faccB (contiguous)

  // P4a: routed experts, 2 groups of 4, fused per group
  for (int g=0; g<2; ++g){
    const int eb = g*4;
    tpose_k<<<dim3(128,32,4),blk,0,stream>>>(rW1 + (long)eb*4194304, Wt_g, 1024, 4096,
                                             4194304L, 4194304L);
    GEMM(F_OUTBF16|F_BIAS|F_RELU|F_GATHER|F_EXPB, dim3(32,32,4),
         h2_bf,1024,0, Wt_g,1024,4194304L, inter,4096,0,
         nullptr, rb1, nullptr, nullptr, idxb, nullptr, cntoff, eb, 1024, 4096);
    tpose_k<<<dim3(32,128,4),blk,0,stream>>>(rW2 + (long)eb*4194304, Wt_g, 4096, 1024,
                                             4194304L, 4194304L);
    GEMM(F_BIAS|F_SCATTER|F_EXPB, dim3(8,32,4),
         inter,4096,0, Wt_g,4096,4194304L, faccA,1024,0,
         faccB, rb2, nullptr, gvb, idxb, slotb, cntoff, eb, 4096, 1024);
  }

  // P4b: shared experts, dense, accumulate into d_out
  for (int j=0;j<2;j++){
    tpose_k<<<dim3(128,32,1),blk,0,stream>>>(sW1 + (long)j*4194304, Wt_g, 1024, 4096, 0,0);
    GEMM(F_OUTBF16|F_BIAS|F_RELU, dim3(32,32,1), h2_bf,1024,0, Wt_g,1024,0, inter,4096,0,
         nullptr, sb1 + j*4096, nullptr,nullptr,nullptr,nullptr,nullptr,0, 1024, 4096);
    tpose_k<<<dim3(32,128,1),blk,0,stream>>>(sW2 + (long)j*4194304, Wt_g, 4096, 1024, 0,0);
    GEMM(F_BIAS|F_GATEACC, dim3(8,32,1), inter,4096,0, Wt_g,4096,0, (float*)d_out,1024,0,
         nullptr, sb2 + j*1024, nullptr,nullptr,nullptr,nullptr,nullptr,0, 4096, 1024);
  }

  // out += faccA + faccB
  addacc_k<<<2048, blk, 0, stream>>>(faccA, faccB, (float*)d_out, 1048576L);
}

// Round 7
// 1334.111 us; speedup vs baseline: 1.7311x; 1.1776x over previous
//
#include <hip/hip_runtime.h>
#include <cstdint>

typedef unsigned short u16;
typedef unsigned int   u32;
typedef unsigned long long u64;
using short8 = __attribute__((ext_vector_type(8))) short;
using f32x4  = __attribute__((ext_vector_type(4))) float;

#define S_   2048
#define D_   1024
#define NTOK 4096   /* B*S */

__device__ __forceinline__ u16 f2bf(float f){
  u32 u = __float_as_uint(f);
  u32 r = u + 0x7fffu + ((u >> 16) & 1u);   // RNE
  return (u16)(r >> 16);
}
__device__ __forceinline__ float bf2f(u16 h){
  return __uint_as_float(((u32)h) << 16);
}
__device__ __forceinline__ void gld16(const void* g, void* l){
  __builtin_amdgcn_global_load_lds((__attribute__((address_space(1))) void*)(void*)g,
                                   (__attribute__((address_space(3))) void*)l, 16, 0, 0);
}

// ---------------------------------------------------------------------------
// bf16 MFMA GEMM (NT): C[M,N] = A[M,K] * Bt[N,K]^T, 128x128x32 tiles, 4 waves.
// F_GATHER : A rows gathered via idx list (expert e=ebase+z, list at off[e]);
//            output rows packed at off[e]+row in `out`.
// F_SCATTER: A rows at off[e]+row of inter; output row -> token via idx;
//            dst = (float*)out + (slot*2+kh)*sOz, '=' write.
// F_EXPB   : bias indexed per expert: bias + (ebase+ze)*ncols.
// F_PVOUT  : z = ks*8+hl; f32 partials [ks][row][hl*64+col].
// F_SPLITK2: z = ze*2+kh; K arg is the HALF length; A/Bt advance kh*K in k;
//            bias applied only on kh==0.
// XCD-aware bijective block swizzle (m204).
// ---------------------------------------------------------------------------
enum { F_OUTBF16=1, F_BIAS=2, F_RELU=4, F_RESID=8, F_GATEACC=16,
       F_GATHER=64, F_SCATTER=128, F_PVOUT=256, F_EXPB=512, F_SPLITK2=1024 };

template<int FLAGS>
__global__ void __launch_bounds__(256, 4)
gemm_k(const u16* __restrict__ A, int lda, long sAz,
       const u16* __restrict__ Bt, int ldb, long sBz,
       void* __restrict__ out, int ldo, long sOz,
       float* __restrict__ out2,
       const float* __restrict__ bias,
       const float* __restrict__ resid,
       const float* __restrict__ gv,
       const int* __restrict__ idx,
       const int* __restrict__ slotb,
       const int* __restrict__ cntp, int ebase,
       int K, int ncols)
{
  constexpr int BM = 128, BK = 32;
  const int tid = threadIdx.x;
  const int w = tid >> 6, l = tid & 63;
  const int wr = w >> 1, wc = w & 1;

  // bijective XCD swizzle
  const int gx = gridDim.x, gy = gridDim.y;
  const int nwg = gx*gy*gridDim.z;
  const int flat = (blockIdx.z*gy + blockIdx.y)*gx + blockIdx.x;
  const int q8 = nwg >> 3, r8 = nwg & 7, xcd = flat & 7, off8 = flat >> 3;
  const int swz = (xcd < r8) ? (xcd*(q8+1) + off8)
                             : (r8*(q8+1) + (xcd-r8)*q8 + off8);
  const int tn = swz % gx;
  const int rest = swz / gx;
  const int tm = rest % gy;
  const int z  = rest / gy;
  const int ncol0 = tn * 128;

  int kh = 0, ze = z;
  if constexpr (FLAGS & F_SPLITK2){ kh = z & 1; ze = z >> 1; }

  int cnt = 0x7fffffff; long ofs = 0;
  if constexpr (FLAGS & (F_GATHER|F_SCATTER)){
    const int e = ebase + ze;
    cnt = cntp[e]; ofs = (long)cntp[8+e];
    if (tm*BM >= cnt) return;
  }

  const u16 *Abase, *Btbase;
  if constexpr (FLAGS & F_PVOUT){
    Abase  = A  + (long)(z&7)*sAz + (long)(z>>3)*K + (long)tm*BM*lda;
    Btbase = Bt + (long)(z&7)*sBz + (long)(z>>3)*K + (long)ncol0*ldb;
  } else if constexpr (FLAGS & F_GATHER){
    Abase  = A;                              // rows via idx
    Btbase = Bt + (long)ze*sBz + (long)ncol0*ldb;
  } else if constexpr (FLAGS & F_SCATTER){
    Abase  = A + ofs*lda + (long)tm*BM*lda + (long)kh*K;
    Btbase = Bt + (long)ze*sBz + (long)ncol0*ldb + (long)kh*K;
  } else {
    Abase  = A  + (long)ze*sAz + (long)tm*BM*lda + (long)kh*K;
    Btbase = Bt + (long)ze*sBz + (long)ncol0*ldb + (long)kh*K;
  }

  const int r0 = tid >> 2, seg = tid & 3;
  long aoff0, aoff1;
  if constexpr (FLAGS & F_GATHER){
    const int p0 = tm*BM + r0, p1 = p0 + 64;
    const int t0 = (p0 < cnt) ? idx[ofs + p0] : 0;
    const int t1 = (p1 < cnt) ? idx[ofs + p1] : 0;
    aoff0 = (long)t0*lda; aoff1 = (long)t1*lda;
  } else {
    aoff0 = (long)r0*lda; aoff1 = (long)(r0+64)*lda;
  }
  const u16* pA0 = Abase + aoff0 + seg*8;
  const u16* pA1 = Abase + aoff1 + seg*8;
  const u16* pB0 = Btbase + (long)r0*ldb + seg*8;
  const u16* pB1 = Btbase + (long)(r0+64)*ldb + seg*8;

  __shared__ __align__(16) u16 As[2][BM*BK];
  __shared__ __align__(16) u16 Bs[2][BM*BK];

  f32x4 zero = {0.f,0.f,0.f,0.f};
  f32x4 acc[4][4];
  #pragma unroll
  for (int i=0;i<4;i++)
    #pragma unroll
    for (int j=0;j<4;j++) acc[i][j] = zero;

  const int NK = K >> 5;

  auto stage = [&](int buf, int kt){
    const int k0 = kt*BK;
    gld16(pA0 + k0, &As[buf][(w*64)*8]);
    gld16(pA1 + k0, &As[buf][(256 + w*64)*8]);
    gld16(pB0 + k0, &Bs[buf][(w*64)*8]);
    gld16(pB1 + k0, &Bs[buf][(256 + w*64)*8]);
  };

  stage(0,0);
  __syncthreads();

  for (int kt=0; kt<NK; ++kt){
    const int cur = kt & 1, nxt = cur ^ 1;
    if (kt+1 < NK) stage(nxt, kt+1);
    short8 a[4], b[4];
    #pragma unroll
    for (int m=0;m<4;m++){
      const int arow = wr*64 + m*16 + (l & 15);
      a[m] = *(const short8*)&As[cur][arow*BK + (l>>4)*8];
    }
    #pragma unroll
    for (int n=0;n<4;n++){
      const int brow = wc*64 + n*16 + (l & 15);
      b[n] = *(const short8*)&Bs[cur][brow*BK + (l>>4)*8];
    }
    #pragma unroll
    for (int m=0;m<4;m++)
      #pragma unroll
      for (int n=0;n<4;n++)
        acc[m][n] = __builtin_amdgcn_mfma_f32_16x16x32_bf16(a[m], b[n], acc[m][n], 0, 0, 0);
    __syncthreads();
  }

  // epilogue  (C/D: col = lane&15, row = (lane>>4)*4 + reg)
  float* outf = (float*)out + (long)z*sOz;
  u16*   outh = (u16*)out + (long)z*sOz;
  float* pvf  = (float*)out + (long)(z>>3)*sOz;   // PVOUT
  const float* bp = bias;
  if constexpr (FLAGS & F_EXPB) bp += (long)(ebase+ze)*ncols;
  const long row0 = (long)tm*BM + wr*64;
  #pragma unroll
  for (int m=0;m<4;m++){
    #pragma unroll
    for (int n=0;n<4;n++){
      const int col = ncol0 + wc*64 + n*16 + (l & 15);
      if (col < ncols){
        #pragma unroll
        for (int r=0;r<4;r++){
          const long row = row0 + m*16 + ((l>>4)*4) + r;
          float v = acc[m][n][r];
          if constexpr (FLAGS & F_BIAS){
            bool addb = true;
            if constexpr (FLAGS & F_SPLITK2) addb = (kh == 0);
            if (addb) v += bp[col];
          }
          if constexpr (FLAGS & F_RELU) v = fmaxf(v, 0.f);
          if constexpr (FLAGS & F_PVOUT){
            pvf[row*(long)ldo + (z&7)*64 + col] = v;
          } else if constexpr (FLAGS & F_SCATTER){
            if (row < cnt){
              const long gs = ofs + row;
              const int tok = idx[gs];
              float* dst = (float*)out + (long)(slotb[gs]*2 + kh)*sOz;
              dst[(long)tok*ldo + col] = gv[gs] * v;
            }
          } else if constexpr (FLAGS & F_GATHER){
            if (row < cnt) outh[(ofs + row)*(long)ldo + col] = f2bf(v);
          } else if constexpr (FLAGS & F_GATEACC){
            outf[row*(long)ldo + col] += v;
          } else if constexpr (FLAGS & F_RESID){
            const long off = row*(long)ldo + col;
            outf[off] = resid[off] + v;
          } else if constexpr (FLAGS & F_OUTBF16){
            outh[row*(long)ldo + col] = f2bf(v);
          } else {
            outf[row*(long)ldo + col] = v;
          }
        }
      }
    }
  }
}

// ---------------------------------------------------------------------------
// batched transpose f32 [K][N] (ld=N) -> bf16 [N][K] (ld=K); z via strides.
__global__ void tpose_k(const float* __restrict__ src, u16* __restrict__ dst,
                        int K, int N, long szS, long szD)
{
  __shared__ u16 tile[32][36];
  const int t = threadIdx.x;
  src += (long)blockIdx.z*szS; dst += (long)blockIdx.z*szD;
  const int n0 = blockIdx.x*32, k0 = blockIdx.y*32;
  const int lr = t >> 3, lc = (t & 7) * 4;
  const float4 v = *(const float4*)&src[(long)(k0+lr)*N + n0 + lc];
  ushort4 tv; tv.x=f2bf(v.x); tv.y=f2bf(v.y); tv.z=f2bf(v.z); tv.w=f2bf(v.w);
  *(ushort4*)&tile[lr][lc] = tv;
  __syncthreads();
  ushort4 o;
  o.x = tile[lc+0][lr]; o.y = tile[lc+1][lr];
  o.z = tile[lc+2][lr]; o.w = tile[lc+3][lr];
  *(ushort4*)&dst[(long)(n0+lr)*K + k0 + lc] = o;
}

// v_bf [b][s][h*64+d] -> vt [(b*16+h)][d][s]
__global__ void vt_k(const u16* __restrict__ src, u16* __restrict__ dst)
{
  __shared__ u16 tile[32][36];
  const int t = threadIdx.x;
  const int z = blockIdx.z;            // b*16+h
  const int b = z >> 4, h = z & 15;
  const int s0 = blockIdx.x*32, d0 = blockIdx.y*32;
  const int lr = t >> 3, lc = (t & 7) * 4;
  ushort4 v = *(const ushort4*)&src[(long)(b*2048 + s0+lr)*1024 + h*64 + d0 + lc];
  *(ushort4*)&tile[lr][lc] = v;
  __syncthreads();
  ushort4 o;
  o.x = tile[lc+0][lr]; o.y = tile[lc+1][lr];
  o.z = tile[lc+2][lr]; o.w = tile[lc+3][lr];
  *(ushort4*)&dst[(long)z*131072 + (long)(d0+lr)*2048 + s0 + lc] = o;
}

// sum two f32 PV partials -> bf16 attn rows
__global__ void pvcomb_k(const float* __restrict__ p, u16* __restrict__ dst)
{
  const int row = blockIdx.x, t = threadIdx.x;
  const float2 v0 = ((const float2*)(p + (long)row*512))[t];
  const float2 v1 = ((const float2*)(p + 1048576 + (long)row*512))[t];
  u32 pk = (u32)f2bf(v0.x+v1.x) | ((u32)f2bf(v0.y+v1.y) << 16);
  *(u32*)&dst[(long)row*1024 + t*2] = pk;
}

// ---------------------------------------------------------------------------
template<bool WF32>
__global__ void rmsnorm_k(const float* __restrict__ x, const float* __restrict__ w,
                          u16* __restrict__ ob, float* __restrict__ of)
{
  const int row = blockIdx.x, t = threadIdx.x;
  const float4 v = ((const float4*)(x + (long)row*D_))[t];
  float ss = v.x*v.x + v.y*v.y + v.z*v.z + v.w*v.w;
  #pragma unroll
  for (int o=32;o>0;o>>=1) ss += __shfl_down(ss, o);
  __shared__ float red[4];
  if ((t&63)==0) red[t>>6] = ss;
  __syncthreads();
  const float scale = rsqrtf((red[0]+red[1]+red[2]+red[3])*(1.0f/D_) + 1e-6f);
  const float4 wv = ((const float4*)w)[t];
  const float o0=v.x*scale*wv.x, o1=v.y*scale*wv.y, o2=v.z*scale*wv.z, o3=v.w*scale*wv.w;
  const long base = (long)row*D_ + t*4;
  uint2 p; p.x = (u32)f2bf(o0) | ((u32)f2bf(o1)<<16);
  p.y = (u32)f2bf(o2) | ((u32)f2bf(o3)<<16);
  *(uint2*)&ob[base] = p;
  if constexpr (WF32) *(float4*)&of[base] = make_float4(o0,o1,o2,o3);
}

// qf = [q | rope(qr)], kf = [k | rope(kr)]
__global__ void rope_concat_k(const u16* __restrict__ qt, const u16* __restrict__ qrt,
                              const u16* __restrict__ kt, const u16* __restrict__ krt,
                              const float* __restrict__ fc, const float* __restrict__ fs,
                              u16* __restrict__ qf, u16* __restrict__ kf)
{
  const int idx = blockIdx.x*256 + threadIdx.x;
  const int j = idx & 31, h = (idx>>5) & 15, bs = idx >> 9;
  if (bs >= NTOK) return;
  const int s = bs & (S_-1);
  const float c = fc[s*32+j], sn = fs[s*32+j];
  const long ib = (long)bs*1024 + h*64 + 2*j;
  const long ob = (long)bs*2048 + h*128 + 2*j;
  *(u32*)&qf[ob] = *(const u32*)&qt[ib];
  *(u32*)&kf[ob] = *(const u32*)&kt[ib];
  float x0 = bf2f(qrt[ib]), x1 = bf2f(qrt[ib+1]);
  *(u32*)&qf[ob+64] = (u32)f2bf(x0*c - x1*sn) | ((u32)f2bf(x0*sn + x1*c) << 16);
  x0 = bf2f(krt[ib]); x1 = bf2f(krt[ib+1]);
  *(u32*)&kf[ob+64] = (u32)f2bf(x0*c - x1*sn) | ((u32)f2bf(x0*sn + x1*c) << 16);
}

// row softmax of scores/8, in place (bf16), row length 2048
__global__ void softmax_k(u16* __restrict__ sc)
{
  const long row = blockIdx.x;
  const int t = threadIdx.x;
  u16* p = sc + row*2048;
  const uint4 raw = ((const uint4*)p)[t];
  float v[8];
  v[0]=bf2f((u16)(raw.x&0xffffu)); v[1]=bf2f((u16)(raw.x>>16));
  v[2]=bf2f((u16)(raw.y&0xffffu)); v[3]=bf2f((u16)(raw.y>>16));
  v[4]=bf2f((u16)(raw.z&0xffffu)); v[5]=bf2f((u16)(raw.z>>16));
  v[6]=bf2f((u16)(raw.w&0xffffu)); v[7]=bf2f((u16)(raw.w>>16));
  float m = v[0];
  #pragma unroll
  for (int i=1;i<8;i++) m = fmaxf(m, v[i]);
  #pragma unroll
  for (int o=32;o>0;o>>=1) m = fmaxf(m, __shfl_down(m, o));
  __shared__ float redm[4], reds[4];
  if ((t&63)==0) redm[t>>6]=m;
  __syncthreads();
  m = fmaxf(fmaxf(redm[0],redm[1]), fmaxf(redm[2],redm[3]));
  float sum = 0.f;
  #pragma unroll
  for (int i=0;i<8;i++){ v[i] = expf((v[i]-m)*0.125f); sum += v[i]; }
  #pragma unroll
  for (int o=32;o>0;o>>=1) sum += __shfl_down(sum, o);
  if ((t&63)==0) reds[t>>6]=sum;
  __syncthreads();
  const float inv = 1.f/(reds[0]+reds[1]+reds[2]+reds[3]);
  uint4 o4;
  o4.x = (u32)f2bf(v[0]*inv) | ((u32)f2bf(v[1]*inv)<<16);
  o4.y = (u32)f2bf(v[2]*inv) | ((u32)f2bf(v[3]*inv)<<16);
  o4.z = (u32)f2bf(v[4]*inv) | ((u32)f2bf(v[5]*inv)<<16);
  o4.w = (u32)f2bf(v[6]*inv) | ((u32)f2bf(v[7]*inv)<<16);
  ((uint4*)p)[t] = o4;
}

// noisy top-2 per token -> eids (i0|i1<<8), gates (g0,g1).  Deterministic.
__global__ void topk_k(const float* __restrict__ h2, const float* __restrict__ wr,
                       const float* __restrict__ br, const float* __restrict__ wn,
                       const float* __restrict__ bn, const float* __restrict__ noise,
                       int* __restrict__ eids, float2* __restrict__ gates)
{
  const int tok = blockIdx.x, t = threadIdx.x;
  const float4 xv = ((const float4*)(h2 + (long)tok*D_))[t];
  const float xs[4] = {xv.x, xv.y, xv.z, xv.w};
  float ar[8], an[8];
  #pragma unroll
  for (int e=0;e<8;e++){ ar[e]=0.f; an[e]=0.f; }
  #pragma unroll
  for (int i=0;i<4;i++){
    const int d = t*4+i;
    const float* wrr = wr + d*8;
    const float* wnr = wn + d*8;
    #pragma unroll
    for (int e=0;e<8;e++){ ar[e] += xs[i]*wrr[e]; an[e] += xs[i]*wnr[e]; }
  }
  #pragma unroll
  for (int e=0;e<8;e++){
    #pragma unroll
    for (int o=32;o>0;o>>=1){ ar[e] += __shfl_down(ar[e], o); an[e] += __shfl_down(an[e], o); }
  }
  __shared__ float rr[4][8], rn[4][8];
  if ((t&63)==0){
    const int w4 = t>>6;
    #pragma unroll
    for (int e=0;e<8;e++){ rr[w4][e]=ar[e]; rn[w4][e]=an[e]; }
  }
  __syncthreads();
  if (t==0){
    float nz[8];
    #pragma unroll
    for (int e=0;e<8;e++){
      const float r  = rr[0][e]+rr[1][e]+rr[2][e]+rr[3][e] + br[e];
      const float ns = rn[0][e]+rn[1][e]+rn[2][e]+rn[3][e] + bn[e];
      const float sp = (ns > 20.f) ? ns : log1pf(expf(ns));
      nz[e] = r + noise[(long)tok*8+e]*sp;
    }
    int i0 = 0;
    #pragma unroll
    for (int e=1;e<8;e++) if (nz[e] > nz[i0]) i0 = e;
    int i1 = -1; float best = -3.0e38f;
    #pragma unroll
    for (int e=0;e<8;e++) if (e != i0 && nz[e] > best){ best = nz[e]; i1 = e; }
    const float e1  = expf(nz[i1]-nz[i0]);
    const float inv = 1.f/(1.f+e1);
    eids[tok] = i0 | (i1 << 8);
    gates[tok] = make_float2(inv, e1*inv);
  }
}

// --- parallel deterministic compact: hist -> scan -> fill --------------------
__global__ void __launch_bounds__(64)
hist_k(const int* __restrict__ eids, int* __restrict__ segcnt)
{
  const int b = blockIdx.x, t = threadIdx.x;
  const int id = eids[b*64 + t];
  const int i0 = id & 255, i1 = (id >> 8) & 255;
  #pragma unroll
  for (int e=0;e<8;e++){
    const u64 m0 = __ballot(i0==e);
    const u64 m1 = __ballot(i1==e);
    if (t==0) segcnt[e*64+b] = __popcll(m0) + __popcll(m1);
  }
}

__global__ void __launch_bounds__(64)
scan_k(const int* __restrict__ segcnt, int* __restrict__ segoff,
       int* __restrict__ cntoff)
{
  const int t = threadIdx.x;
  int base = 0;
  for (int e=0;e<8;e++){
    const int c = segcnt[e*64+t];
    int sc = c;
    #pragma unroll
    for (int o=1;o<64;o<<=1){ int u = __shfl_up(sc, o); if (t >= o) sc += u; }
    const int tot = __shfl(sc, 63);
    segoff[e*64+t] = base + (sc - c);
    if (t==0){ cntoff[e] = tot; cntoff[8+e] = base; }
    base += tot;
  }
}

__global__ void __launch_bounds__(64)
fill_k(const int* __restrict__ eids, const float2* __restrict__ gates,
       const int* __restrict__ segoff, int* __restrict__ idxb,
       float* __restrict__ gvb, int* __restrict__ slotb)
{
  const int b = blockIdx.x, t = threadIdx.x;
  const int tok = b*64 + t;
  const int id = eids[tok];
  const int i0 = id & 255, i1 = (id >> 8) & 255;
  const float2 g = gates[tok];
  const u64 below = ((u64)1 << t) - 1;
  #pragma unroll
  for (int e=0;e<8;e++){
    const u64 m0 = __ballot(i0==e);
    const u64 m1 = __ballot(i1==e);
    if (i0==e){
      const int pos = segoff[e*64+b] + __popcll(m0 & below);
      idxb[pos] = tok; gvb[pos] = g.x; slotb[pos] = 0;
    } else if (i1==e){
      const int pos = segoff[e*64+b] + __popcll(m0) + __popcll(m1 & below);
      idxb[pos] = tok; gvb[pos] = g.y; slotb[pos] = 1;
    }
  }
}

// o = a + b
__global__ void addstore_k(const float* __restrict__ a, const float* __restrict__ b,
                           float* __restrict__ o, long n4)
{
  long i = (long)blockIdx.x*blockDim.x + threadIdx.x;
  const long stride = (long)gridDim.x*blockDim.x;
  for (; i<n4; i+=stride){
    const float4 va = ((const float4*)a)[i];
    const float4 vb = ((const float4*)b)[i];
    ((float4*)o)[i] = make_float4(va.x+vb.x, va.y+vb.y, va.z+vb.z, va.w+vb.w);
  }
}
// o += f0+f1+f2+f3
__global__ void addacc4_k(const float* __restrict__ f0, const float* __restrict__ f1,
                          const float* __restrict__ f2, const float* __restrict__ f3,
                          float* __restrict__ o, long n4)
{
  long i = (long)blockIdx.x*blockDim.x + threadIdx.x;
  const long stride = (long)gridDim.x*blockDim.x;
  for (; i<n4; i+=stride){
    const float4 a = ((const float4*)f0)[i];
    const float4 b = ((const float4*)f1)[i];
    const float4 c = ((const float4*)f2)[i];
    const float4 d = ((const float4*)f3)[i];
    float4 vo = ((const float4*)o)[i];
    ((float4*)o)[i] = make_float4(vo.x+a.x+b.x+c.x+d.x, vo.y+a.y+b.y+c.y+d.y,
                                  vo.z+a.z+b.z+c.z+d.z, vo.w+a.w+b.w+c.w+d.w);
  }
}

// ---------------------------------------------------------------------------
extern "C" void kernel_launch(void* const* d_in, const int* in_sizes, int n_in,
                              void* d_out, int out_size, void* d_ws, size_t ws_size,
                              hipStream_t stream)
{
  const float* x      = (const float*)d_in[0];
  const float* fcos   = (const float*)d_in[1];
  const float* fsin   = (const float*)d_in[2];
  const float* rnoise = (const float*)d_in[3];
  const float* rms1w  = (const float*)d_in[4];
  const float* rms2w  = (const float*)d_in[5];
  const float* w_lq   = (const float*)d_in[6];
  const float* w_lkv  = (const float*)d_in[7];
  const float* w_q    = (const float*)d_in[8];
  const float* w_k    = (const float*)d_in[9];
  const float* w_v    = (const float*)d_in[10];
  const float* w_qr   = (const float*)d_in[11];
  const float* b_qr   = (const float*)d_in[12];
  const float* w_kr   = (const float*)d_in[13];
  const float* b_kr   = (const float*)d_in[14];
  const float* w_o    = (const float*)d_in[15];
  const float* b_o    = (const float*)d_in[16];
  const float* w_route= (const float*)d_in[17];
  const float* b_route= (const float*)d_in[18];
  const float* w_noise= (const float*)d_in[19];
  const float* b_noise= (const float*)d_in[20];
  const float* rW1    = (const float*)d_in[21];
  const float* rb1    = (const float*)d_in[22];
  const float* rW2    = (const float*)d_in[23];
  const float* rb2    = (const float*)d_in[24];
  const float* sW1    = (const float*)d_in[25];
  const float* sb1    = (const float*)d_in[26];
  const float* sW2    = (const float*)d_in[27];
  const float* sb2    = (const float*)d_in[28];

  if (ws_size < 195166208ULL) return;

  char* ws = (char*)d_ws;
  // persistent / phased buffers
  u16*   h_bf    = (u16*)(ws + 0);           // P1
  u16*   cq_bf   = (u16*)(ws + 8388608);     // P1
  u16*   ckv_bf  = (u16*)(ws + 14680064);    // P1
  u16*   v_bf    = (u16*)(ws + 18874368);    // P1
  u16*   qf      = (u16*)(ws + 27262976);    // P1-P2, 16 MiB
  u16*   kf      = (u16*)(ws + 44040192);    // P1-P2, 16 MiB
  u16*   vt      = (u16*)(ws + 60817408);    // P1-P2, 8.25 MiB -> 69468160
  u16*   attn_bf = (u16*)(ws + 69468160);    // P2-P3, 8 MiB
  float* x1      = (float*)(ws + 77856768);  // P3 (dead after addstore)
  float* h2f     = (float*)(ws + 94633984);  // P3 (dead after addstore)
  u16*   h2_bf   = (u16*)(ws + 111411200);   // P3-P4, 8 MiB
  float* fb      = (float*)(ws + 119799808); // P4: 4 x 16 MiB partials -> 186908672
  u16*   Wt_g    = (u16*)(ws + 77856768);    // P4: 32 MiB (x1/h2f zone) -> 111411200
  int*   cntoff  = (int*)(ws + 189005824);   // 16 ints
  int*   eids    = (int*)(ws + 189006080);
  float2* gatesb = (float2*)(ws + 189022464);
  int*   idxb    = (int*)(ws + 189055232);
  float* gvb     = (float*)(ws + 189088000);
  int*   slotb   = (int*)(ws + 189120768);   // ends 189153536
  u16*   wo_t    = (u16*)(ws + 189153536);   // 2 MiB -> 191250560
  int*   segcnt  = (int*)(ws + 191250560);   // 2 KiB
  int*   segoff  = (int*)(ws + 191252608);   // 2 KiB
  // temporal overlays
  u16*   q_tmp   = (u16*)(ws + 77856768);    // P1
  u16*   qr_tmp  = (u16*)(ws + 86245376);
  u16*   k_tmp   = (u16*)(ws + 94633984);
  u16*   kr_tmp  = (u16*)(ws + 103022592);
  u16*   scores  = (u16*)(ws + 77856768);    // P2, 64 MiB
  float* pvpart  = (float*)(ws + 146538496); // P2, 8 MiB
  u16*   inter   = (u16*)(ws + 0);           // P4, 64 MiB (8192 x 4096 bf16)
  // small weight transposes (P1 zone, overlaid on fb region)
  u16*   wlq_t   = (u16*)(ws + 119799808);
  u16*   wlkv_t  = (u16*)(ws + 121372672);
  u16*   wq_t    = (u16*)(ws + 122421248);
  u16*   wqr_t   = (u16*)(ws + 123994112);
  u16*   wk_t    = (u16*)(ws + 125566976);
  u16*   wkr_t   = (u16*)(ws + 126615552);
  u16*   wv_t    = (u16*)(ws + 128712704);

  const dim3 blk(256,1,1);
  #define GEMM(FL, GRID, ...) gemm_k<FL><<<GRID, blk, 0, stream>>>(__VA_ARGS__)
  #define NOSPARSE nullptr,nullptr,nullptr,nullptr,nullptr,nullptr,nullptr,0

  // P0: small weight transposes (f32 [K][N] -> bf16 [N][K])
  tpose_k<<<dim3(24,32),blk,0,stream>>>(w_lq,  wlq_t, 1024, 768, 0,0);
  tpose_k<<<dim3(16,32),blk,0,stream>>>(w_lkv, wlkv_t,1024, 512, 0,0);
  tpose_k<<<dim3(32,24),blk,0,stream>>>(w_q,   wq_t,   768,1024, 0,0);
  tpose_k<<<dim3(32,24),blk,0,stream>>>(w_qr,  wqr_t,  768,1024, 0,0);
  tpose_k<<<dim3(32,16),blk,0,stream>>>(w_k,   wk_t,   512,1024, 0,0);
  tpose_k<<<dim3(32,32),blk,0,stream>>>(w_kr,  wkr_t, 1024,1024, 0,0);
  tpose_k<<<dim3(32,16),blk,0,stream>>>(w_v,   wv_t,   512,1024, 0,0);
  tpose_k<<<dim3(32,32),blk,0,stream>>>(w_o,   wo_t,  1024,1024, 0,0);

  // P1: rmsnorm + projections + rope
  rmsnorm_k<false><<<NTOK, blk, 0, stream>>>(x, rms1w, h_bf, nullptr);

  GEMM(F_OUTBF16, dim3(6,32,1),  h_bf,1024,0,  wlq_t,1024,0,  cq_bf,768,0,  NOSPARSE, 1024, 768);
  GEMM(F_OUTBF16, dim3(4,32,1),  h_bf,1024,0,  wlkv_t,1024,0, ckv_bf,512,0, NOSPARSE, 1024, 512);
  GEMM(F_OUTBF16, dim3(8,32,1),  cq_bf,768,0,  wq_t,768,0,    q_tmp,1024,0, NOSPARSE, 768, 1024);
  GEMM(F_OUTBF16|F_BIAS, dim3(8,32,1), cq_bf,768,0, wqr_t,768,0, qr_tmp,1024,0,
       nullptr, b_qr, nullptr,nullptr,nullptr,nullptr,nullptr,0, 768, 1024);
  GEMM(F_OUTBF16, dim3(8,32,1),  ckv_bf,512,0, wk_t,512,0,    k_tmp,1024,0, NOSPARSE, 512, 1024);
  GEMM(F_OUTBF16|F_BIAS, dim3(8,32,1), h_bf,1024,0, wkr_t,1024,0, kr_tmp,1024,0,
       nullptr, b_kr, nullptr,nullptr,nullptr,nullptr,nullptr,0, 1024, 1024);
  GEMM(F_OUTBF16, dim3(8,32,1),  ckv_bf,512,0, wv_t,512,0,    v_bf,1024,0,  NOSPARSE, 512, 1024);

  rope_concat_k<<<8192, blk, 0, stream>>>(q_tmp, qr_tmp, k_tmp, kr_tmp, fcos, fsin, qf, kf);
  vt_k<<<dim3(64,2,32), blk, 0, stream>>>(v_bf, vt);

  // P2: attention, 4 chunks of 8 heads; PV split-K x2 (256 blocks)
  for (int c=0;c<4;c++){
    const int b = c >> 1, h0 = (c & 1) * 8;
    const u16* qfs = qf + (long)b*4194304 + h0*128;
    const u16* kfs = kf + (long)b*4194304 + h0*128;
    GEMM(F_OUTBF16, dim3(16,16,8), qfs,2048,128, kfs,2048,128, scores,2048,4194304L,
         NOSPARSE, 128, 2048);
    softmax_k<<<16384, blk, 0, stream>>>(scores);
    const u16* vs = vt + (long)(b*16 + h0)*131072;
    GEMM(F_PVOUT, dim3(1,16,16), scores,2048,4194304L, vs,2048,131072L, pvpart,512,1048576L,
         NOSPARSE, 1024, 64);
    pvcomb_k<<<2048, blk, 0, stream>>>(pvpart, attn_bf + (long)b*2097152 + h0*64);
  }

  // P3: o-proj + rmsnorm2 + router
  GEMM(F_BIAS|F_RESID, dim3(8,32,1), attn_bf,1024,0, wo_t,1024,0, x1,1024,0,
       nullptr, b_o, x, nullptr,nullptr,nullptr,nullptr,0, 1024, 1024);
  rmsnorm_k<true><<<NTOK, blk, 0, stream>>>(x1, rms2w, h2_bf, h2f);
  topk_k<<<NTOK, blk, 0, stream>>>(h2f, w_route, b_route, w_noise, b_noise, rnoise,
                                   eids, gatesb);
  hist_k<<<64, 64, 0, stream>>>(eids, segcnt);
  scan_k<<<1, 64, 0, stream>>>(segcnt, segoff, cntoff);
  fill_k<<<64, 64, 0, stream>>>(eids, gatesb, segoff, idxb, gvb, slotb);
  addstore_k<<<2048, blk, 0, stream>>>(x1, h2f, (float*)d_out, 1048576L);  // out = x1+h2
  hipMemsetAsync(fb, 0, 67108864, stream);   // zero 4x16MiB partials

  // P4a: routed experts, 2 groups of 4; G2 split-K x2 into fb[slot*2+kh]
  for (int g=0; g<2; ++g){
    const int eb = g*4;
    tpose_k<<<dim3(128,32,4),blk,0,stream>>>(rW1 + (long)eb*4194304, Wt_g, 1024, 4096,
                                             4194304L, 4194304L);
    GEMM(F_OUTBF16|F_BIAS|F_RELU|F_GATHER|F_EXPB, dim3(32,32,4),
         h2_bf,1024,0, Wt_g,1024,4194304L, inter,4096,0,
         nullptr, rb1, nullptr, nullptr, idxb, nullptr, cntoff, eb, 1024, 4096);
    tpose_k<<<dim3(32,128,4),blk,0,stream>>>(rW2 + (long)eb*4194304, Wt_g, 4096, 1024,
                                             4194304L, 4194304L);
    GEMM(F_BIAS|F_SCATTER|F_EXPB|F_SPLITK2, dim3(8,32,8),
         inter,4096,0, Wt_g,4096,4194304L, fb,1024,4194304L,
         nullptr, rb2, nullptr, gvb, idxb, slotb, cntoff, eb, 2048, 1024);
  }

  // P4b: shared experts, dense; G2 split-K x2, += into fb[j*2+kh]
  for (int j=0;j<2;j++){
    tpose_k<<<dim3(128,32,1),blk,0,stream>>>(sW1 + (long)j*4194304, Wt_g, 1024, 4096, 0,0);
    GEMM(F_OUTBF16|F_BIAS|F_RELU, dim3(32,32,1), h2_bf,1024,0, Wt_g,1024,0, inter,4096,0,
         nullptr, sb1 + j*4096, nullptr,nullptr,nullptr,nullptr,nullptr,0, 1024, 4096);
    tpose_k<<<dim3(32,128,1),blk,0,stream>>>(sW2 + (long)j*4194304, Wt_g, 4096, 1024, 0,0);
    GEMM(F_BIAS|F_GATEACC|F_SPLITK2, dim3(8,32,2),
         inter,4096,0, Wt_g,4096,0, fb + (long)j*2*4194304L,1024,4194304L,
         nullptr, sb2 + j*1024, nullptr,nullptr,nullptr,nullptr,nullptr,0, 2048, 1024);
  }

  // out += fb0+fb1+fb2+fb3
  addacc4_k<<<2048, blk, 0, stream>>>(fb, fb+4194304L, fb+8388608L, fb+12582912L,
                                      (float*)d_out, 1048576L);
}

// Round 8
// 1177.309 us; speedup vs baseline: 1.9617x; 1.1332x over previous
//
#include <hip/hip_runtime.h>
#include <cstdint>

typedef unsigned short u16;
typedef unsigned int   u32;
typedef unsigned long long u64;
using short8 = __attribute__((ext_vector_type(8))) short;
using f32x4  = __attribute__((ext_vector_type(4))) float;

#define S_   2048
#define D_   1024
#define NTOK 4096   /* B*S */

__device__ __forceinline__ u16 f2bf(float f){
  u32 u = __float_as_uint(f);
  u32 r = u + 0x7fffu + ((u >> 16) & 1u);   // RNE
  return (u16)(r >> 16);
}
__device__ __forceinline__ float bf2f(u16 h){
  return __uint_as_float(((u32)h) << 16);
}
__device__ __forceinline__ void gld16(const void* g, void* l){
  __builtin_amdgcn_global_load_lds((__attribute__((address_space(1))) void*)(void*)g,
                                   (__attribute__((address_space(3))) void*)l, 16, 0, 0);
}

// ---------------------------------------------------------------------------
// bf16 MFMA GEMM (NT): C[M,N] = A[M,K] * Bt[N,K]^T, 128x128x32 tiles, 4 waves.
// ---------------------------------------------------------------------------
enum { F_OUTBF16=1, F_BIAS=2, F_RELU=4, F_RESID=8, F_GATEACC=16,
       F_GATHER=64, F_SCATTER=128, F_EXPB=512, F_SPLITK2=1024 };

template<int FLAGS>
__global__ void __launch_bounds__(256, 4)
gemm_k(const u16* __restrict__ A, int lda, long sAz,
       const u16* __restrict__ Bt, int ldb, long sBz,
       void* __restrict__ out, int ldo, long sOz,
       float* __restrict__ out2,
       const float* __restrict__ bias,
       const float* __restrict__ resid,
       const float* __restrict__ gv,
       const int* __restrict__ idx,
       const int* __restrict__ slotb,
       const int* __restrict__ cntp, int ebase,
       int K, int ncols)
{
  constexpr int BM = 128, BK = 32;
  const int tid = threadIdx.x;
  const int w = tid >> 6, l = tid & 63;
  const int wr = w >> 1, wc = w & 1;

  // bijective XCD swizzle
  const int gx = gridDim.x, gy = gridDim.y;
  const int nwg = gx*gy*gridDim.z;
  const int flat = (blockIdx.z*gy + blockIdx.y)*gx + blockIdx.x;
  const int q8 = nwg >> 3, r8 = nwg & 7, xcd = flat & 7, off8 = flat >> 3;
  const int swz = (xcd < r8) ? (xcd*(q8+1) + off8)
                             : (r8*(q8+1) + (xcd-r8)*q8 + off8);
  const int tn = swz % gx;
  const int rest = swz / gx;
  const int tm = rest % gy;
  const int z  = rest / gy;
  const int ncol0 = tn * 128;

  int kh = 0, ze = z;
  if constexpr (FLAGS & F_SPLITK2){ kh = z & 1; ze = z >> 1; }

  int cnt = 0x7fffffff; long ofs = 0;
  if constexpr (FLAGS & (F_GATHER|F_SCATTER)){
    const int e = ebase + ze;
    cnt = cntp[e]; ofs = (long)cntp[8+e];
    if (tm*BM >= cnt) return;
  }

  const u16 *Abase, *Btbase;
  if constexpr (FLAGS & F_GATHER){
    Abase  = A;                              // rows via idx
    Btbase = Bt + (long)ze*sBz + (long)ncol0*ldb;
  } else if constexpr (FLAGS & F_SCATTER){
    Abase  = A + ofs*lda + (long)tm*BM*lda + (long)kh*K;
    Btbase = Bt + (long)ze*sBz + (long)ncol0*ldb + (long)kh*K;
  } else {
    Abase  = A  + (long)ze*sAz + (long)tm*BM*lda + (long)kh*K;
    Btbase = Bt + (long)ze*sBz + (long)ncol0*ldb + (long)kh*K;
  }

  const int r0 = tid >> 2, seg = tid & 3;
  long aoff0, aoff1;
  if constexpr (FLAGS & F_GATHER){
    const int p0 = tm*BM + r0, p1 = p0 + 64;
    const int t0 = (p0 < cnt) ? idx[ofs + p0] : 0;
    const int t1 = (p1 < cnt) ? idx[ofs + p1] : 0;
    aoff0 = (long)t0*lda; aoff1 = (long)t1*lda;
  } else {
    aoff0 = (long)r0*lda; aoff1 = (long)(r0+64)*lda;
  }
  const u16* pA0 = Abase + aoff0 + seg*8;
  const u16* pA1 = Abase + aoff1 + seg*8;
  const u16* pB0 = Btbase + (long)r0*ldb + seg*8;
  const u16* pB1 = Btbase + (long)(r0+64)*ldb + seg*8;

  __shared__ __align__(16) u16 As[2][BM*BK];
  __shared__ __align__(16) u16 Bs[2][BM*BK];

  f32x4 zero = {0.f,0.f,0.f,0.f};
  f32x4 acc[4][4];
  #pragma unroll
  for (int i=0;i<4;i++)
    #pragma unroll
    for (int j=0;j<4;j++) acc[i][j] = zero;

  const int NK = K >> 5;

  auto stage = [&](int buf, int kt){
    const int k0 = kt*BK;
    gld16(pA0 + k0, &As[buf][(w*64)*8]);
    gld16(pA1 + k0, &As[buf][(256 + w*64)*8]);
    gld16(pB0 + k0, &Bs[buf][(w*64)*8]);
    gld16(pB1 + k0, &Bs[buf][(256 + w*64)*8]);
  };

  stage(0,0);
  __syncthreads();

  for (int kt=0; kt<NK; ++kt){
    const int cur = kt & 1, nxt = cur ^ 1;
    if (kt+1 < NK) stage(nxt, kt+1);
    short8 a[4], b[4];
    #pragma unroll
    for (int m=0;m<4;m++){
      const int arow = wr*64 + m*16 + (l & 15);
      a[m] = *(const short8*)&As[cur][arow*BK + (l>>4)*8];
    }
    #pragma unroll
    for (int n=0;n<4;n++){
      const int brow = wc*64 + n*16 + (l & 15);
      b[n] = *(const short8*)&Bs[cur][brow*BK + (l>>4)*8];
    }
    #pragma unroll
    for (int m=0;m<4;m++)
      #pragma unroll
      for (int n=0;n<4;n++)
        acc[m][n] = __builtin_amdgcn_mfma_f32_16x16x32_bf16(a[m], b[n], acc[m][n], 0, 0, 0);
    __syncthreads();
  }

  // epilogue  (C/D: col = lane&15, row = (lane>>4)*4 + reg)
  float* outf = (float*)out + (long)z*sOz;
  u16*   outh = (u16*)out + (long)z*sOz;
  const float* bp = bias;
  if constexpr (FLAGS & F_EXPB) bp += (long)(ebase+ze)*ncols;
  const long row0 = (long)tm*BM + wr*64;
  #pragma unroll
  for (int m=0;m<4;m++){
    #pragma unroll
    for (int n=0;n<4;n++){
      const int col = ncol0 + wc*64 + n*16 + (l & 15);
      if (col < ncols){
        #pragma unroll
        for (int r=0;r<4;r++){
          const long row = row0 + m*16 + ((l>>4)*4) + r;
          float v = acc[m][n][r];
          if constexpr (FLAGS & F_BIAS){
            bool addb = true;
            if constexpr (FLAGS & F_SPLITK2) addb = (kh == 0);
            if (addb) v += bp[col];
          }
          if constexpr (FLAGS & F_RELU) v = fmaxf(v, 0.f);
          if constexpr (FLAGS & F_SCATTER){
            if (row < cnt){
              const long gs = ofs + row;
              const int tok = idx[gs];
              float* dst = (float*)out + (long)(slotb[gs]*2 + kh)*sOz;
              dst[(long)tok*ldo + col] = gv[gs] * v;
            }
          } else if constexpr (FLAGS & F_GATHER){
            if (row < cnt) outh[(ofs + row)*(long)ldo + col] = f2bf(v);
          } else if constexpr (FLAGS & F_GATEACC){
            outf[row*(long)ldo + col] += v;
          } else if constexpr (FLAGS & F_RESID){
            const long off = row*(long)ldo + col;
            outf[off] = resid[off] + v;
          } else if constexpr (FLAGS & F_OUTBF16){
            outh[row*(long)ldo + col] = f2bf(v);
          } else {
            outf[row*(long)ldo + col] = v;
          }
        }
      }
    }
  }
}

// ---------------------------------------------------------------------------
// Flash attention: one block per (bh, 128-row q-tile).  4 waves x 32 q-rows.
// qf/kf: [b][s][h*128+d] ld 2048 (concat layout); vt: [bh][d][s] ld 2048.
// Online softmax over 16 KV tiles of 128 keys.  P overwrites K's LDS.
// ---------------------------------------------------------------------------
#define LDP 136   /* padded LDS row: 136 elems = 272B -> 2-way conflicts max */

__global__ void __launch_bounds__(256, 2)
flash_k(const u16* __restrict__ qf, const u16* __restrict__ kf,
        const u16* __restrict__ vt, u16* __restrict__ attn)
{
  const int bh = blockIdx.x;          // x = bh for XCD L2 locality
  const int qt = blockIdx.y;
  const int b = bh >> 4, h = bh & 15;
  const int tid = threadIdx.x, w = tid >> 6, l = tid & 63;
  const int l4 = l & 15, lh = l >> 4;

  const u16* Qb = qf + (long)b*4194304 + h*128;
  const u16* Kb = kf + (long)b*4194304 + h*128;
  const u16* Vb = vt + (long)bh*131072;
  u16* Ob = attn + (long)b*2097152 + h*64;

  // Q a-frags (held in regs for the whole kernel)
  short8 qa[2][4];
  #pragma unroll
  for (int m=0;m<2;m++)
    #pragma unroll
    for (int ks=0;ks<4;ks++){
      const long row = qt*128 + w*32 + m*16 + l4;
      qa[m][ks] = *(const short8*)(Qb + row*2048 + ks*32 + lh*8);
    }

  __shared__ __align__(16) u16 KPs[128*LDP];   // K tile, then P tile
  __shared__ __align__(16) u16 Vs[64*LDP];

  const float SCL = 0.125f * 1.44269504f;      // /sqrt(64), base-2
  float mst[2][4], lst[2][4];
  f32x4 o_acc[2][4];
  #pragma unroll
  for (int m=0;m<2;m++)
    #pragma unroll
    for (int r=0;r<4;r++){ mst[m][r] = -3.0e38f; lst[m][r] = 0.f; }
  #pragma unroll
  for (int m=0;m<2;m++)
    #pragma unroll
    for (int n=0;n<4;n++) o_acc[m][n] = (f32x4){0.f,0.f,0.f,0.f};

  for (int t=0;t<16;t++){
    // stage K tile [128 keys][128 d] and V tile [64 d][128 keys]
    #pragma unroll
    for (int i=0;i<8;i++){
      const int c = i*256 + tid;
      const int kr = c >> 4, kc = (c & 15) * 8;
      const uint4 v = *(const uint4*)(Kb + (long)(t*128+kr)*2048 + kc);
      *(uint4*)&KPs[kr*LDP + kc] = v;
    }
    #pragma unroll
    for (int i=0;i<4;i++){
      const int c = i*256 + tid;
      const int vr = c >> 4, vc = (c & 15) * 8;
      const uint4 v = *(const uint4*)(Vb + (long)vr*2048 + t*128 + vc);
      *(uint4*)&Vs[vr*LDP + vc] = v;
    }
    __syncthreads();

    // S = Q K^T  (per wave: 32 rows x 128 keys)
    f32x4 s[2][8];
    #pragma unroll
    for (int m=0;m<2;m++)
      #pragma unroll
      for (int n=0;n<8;n++) s[m][n] = (f32x4){0.f,0.f,0.f,0.f};
    #pragma unroll
    for (int ks=0;ks<4;ks++){
      short8 bn[8];
      #pragma unroll
      for (int n=0;n<8;n++)
        bn[n] = *(const short8*)&KPs[(n*16+l4)*LDP + ks*32 + lh*8];
      #pragma unroll
      for (int m=0;m<2;m++)
        #pragma unroll
        for (int n=0;n<8;n++)
          s[m][n] = __builtin_amdgcn_mfma_f32_16x16x32_bf16(qa[m][ks], bn[n], s[m][n], 0,0,0);
    }
    __syncthreads();   // K reads done; P may overwrite

    // online softmax (rows live on (m, lh, r); cols on (n, l4))
    #pragma unroll
    for (int m=0;m<2;m++){
      #pragma unroll
      for (int r=0;r<4;r++){
        float pm = s[m][0][r];
        #pragma unroll
        for (int n=1;n<8;n++) pm = fmaxf(pm, s[m][n][r]);
        #pragma unroll
        for (int o=1;o<16;o<<=1) pm = fmaxf(pm, __shfl_xor(pm, o));
        const float mnew = fmaxf(mst[m][r], pm);
        const float sf = exp2f((mst[m][r] - mnew)*SCL);
        float rs = 0.f;
        #pragma unroll
        for (int n=0;n<8;n++){
          float p0 = exp2f((s[m][n][0*0+ r] - mnew)*SCL); // per-reg below
          (void)p0;
        }
        // compute p, rowsum, and store P (done per n,r to keep regs tight)
        float rsum = 0.f;
        #pragma unroll
        for (int n=0;n<8;n++){
          const float p = exp2f((s[m][n][r] - mnew)*SCL);
          s[m][n][r] = p;           // reuse s as P storage
          rsum += p;
        }
        #pragma unroll
        for (int o=1;o<16;o<<=1) rsum += __shfl_xor(rsum, o);
        lst[m][r] = lst[m][r]*sf + rsum;
        mst[m][r] = mnew;
        #pragma unroll
        for (int n=0;n<4;n++) o_acc[m][n][r] *= sf;
        rs = 0.f; (void)rs;
      }
    }
    // write P (bf16) into KPs: row = w*32 + m*16 + lh*4 + r, col = n*16 + l4
    #pragma unroll
    for (int m=0;m<2;m++)
      #pragma unroll
      for (int n=0;n<8;n++)
        #pragma unroll
        for (int r=0;r<4;r++)
          KPs[(w*32 + m*16 + lh*4 + r)*LDP + n*16 + l4] = f2bf(s[m][n][r]);
    __syncthreads();

    // PV: O += P (32x128) * V^T-tile (keys x 64)
    #pragma unroll
    for (int ks=0;ks<4;ks++){
      short8 pa[2], vb[4];
      #pragma unroll
      for (int m=0;m<2;m++)
        pa[m] = *(const short8*)&KPs[(w*32 + m*16 + l4)*LDP + ks*32 + lh*8];
      #pragma unroll
      for (int n=0;n<4;n++)
        vb[n] = *(const short8*)&Vs[(n*16+l4)*LDP + ks*32 + lh*8];
      #pragma unroll
      for (int m=0;m<2;m++)
        #pragma unroll
        for (int n=0;n<4;n++)
          o_acc[m][n] = __builtin_amdgcn_mfma_f32_16x16x32_bf16(pa[m], vb[n], o_acc[m][n], 0,0,0);
    }
    __syncthreads();   // P/V reads done before next stage
  }

  // epilogue: O / l -> bf16
  #pragma unroll
  for (int m=0;m<2;m++){
    #pragma unroll
    for (int r=0;r<4;r++){
      const long row = qt*128 + w*32 + m*16 + lh*4 + r;
      const float inv = 1.f / lst[m][r];
      #pragma unroll
      for (int n=0;n<4;n++)
        Ob[row*1024 + n*16 + l4] = f2bf(o_acc[m][n][r] * inv);
    }
  }
}

// ---------------------------------------------------------------------------
// batched transpose f32 [K][N] (ld=N) -> bf16 [N][K] (ld=K); z via strides.
__global__ void tpose_k(const float* __restrict__ src, u16* __restrict__ dst,
                        int K, int N, long szS, long szD)
{
  __shared__ u16 tile[32][36];
  const int t = threadIdx.x;
  src += (long)blockIdx.z*szS; dst += (long)blockIdx.z*szD;
  const int n0 = blockIdx.x*32, k0 = blockIdx.y*32;
  const int lr = t >> 3, lc = (t & 7) * 4;
  const float4 v = *(const float4*)&src[(long)(k0+lr)*N + n0 + lc];
  ushort4 tv; tv.x=f2bf(v.x); tv.y=f2bf(v.y); tv.z=f2bf(v.z); tv.w=f2bf(v.w);
  *(ushort4*)&tile[lr][lc] = tv;
  __syncthreads();
  ushort4 o;
  o.x = tile[lc+0][lr]; o.y = tile[lc+1][lr];
  o.z = tile[lc+2][lr]; o.w = tile[lc+3][lr];
  *(ushort4*)&dst[(long)(n0+lr)*K + k0 + lc] = o;
}

// v_bf [b][s][h*64+d] -> vt [(b*16+h)][d][s]
__global__ void vt_k(const u16* __restrict__ src, u16* __restrict__ dst)
{
  __shared__ u16 tile[32][36];
  const int t = threadIdx.x;
  const int z = blockIdx.z;            // b*16+h
  const int b = z >> 4, h = z & 15;
  const int s0 = blockIdx.x*32, d0 = blockIdx.y*32;
  const int lr = t >> 3, lc = (t & 7) * 4;
  ushort4 v = *(const ushort4*)&src[(long)(b*2048 + s0+lr)*1024 + h*64 + d0 + lc];
  *(ushort4*)&tile[lr][lc] = v;
  __syncthreads();
  ushort4 o;
  o.x = tile[lc+0][lr]; o.y = tile[lc+1][lr];
  o.z = tile[lc+2][lr]; o.w = tile[lc+3][lr];
  *(ushort4*)&dst[(long)z*131072 + (long)(d0+lr)*2048 + s0 + lc] = o;
}

// ---------------------------------------------------------------------------
template<bool WF32>
__global__ void rmsnorm_k(const float* __restrict__ x, const float* __restrict__ w,
                          u16* __restrict__ ob, float* __restrict__ of)
{
  const int row = blockIdx.x, t = threadIdx.x;
  const float4 v = ((const float4*)(x + (long)row*D_))[t];
  float ss = v.x*v.x + v.y*v.y + v.z*v.z + v.w*v.w;
  #pragma unroll
  for (int o=32;o>0;o>>=1) ss += __shfl_down(ss, o);
  __shared__ float red[4];
  if ((t&63)==0) red[t>>6] = ss;
  __syncthreads();
  const float scale = rsqrtf((red[0]+red[1]+red[2]+red[3])*(1.0f/D_) + 1e-6f);
  const float4 wv = ((const float4*)w)[t];
  const float o0=v.x*scale*wv.x, o1=v.y*scale*wv.y, o2=v.z*scale*wv.z, o3=v.w*scale*wv.w;
  const long base = (long)row*D_ + t*4;
  uint2 p; p.x = (u32)f2bf(o0) | ((u32)f2bf(o1)<<16);
  p.y = (u32)f2bf(o2) | ((u32)f2bf(o3)<<16);
  *(uint2*)&ob[base] = p;
  if constexpr (WF32) *(float4*)&of[base] = make_float4(o0,o1,o2,o3);
}

// qf = [q | rope(qr)], kf = [k | rope(kr)]
__global__ void rope_concat_k(const u16* __restrict__ qt, const u16* __restrict__ qrt,
                              const u16* __restrict__ kt, const u16* __restrict__ krt,
                              const float* __restrict__ fc, const float* __restrict__ fs,
                              u16* __restrict__ qf, u16* __restrict__ kf)
{
  const int idx = blockIdx.x*256 + threadIdx.x;
  const int j = idx & 31, h = (idx>>5) & 15, bs = idx >> 9;
  if (bs >= NTOK) return;
  const int s = bs & (S_-1);
  const float c = fc[s*32+j], sn = fs[s*32+j];
  const long ib = (long)bs*1024 + h*64 + 2*j;
  const long ob = (long)bs*2048 + h*128 + 2*j;
  *(u32*)&qf[ob] = *(const u32*)&qt[ib];
  *(u32*)&kf[ob] = *(const u32*)&kt[ib];
  float x0 = bf2f(qrt[ib]), x1 = bf2f(qrt[ib+1]);
  *(u32*)&qf[ob+64] = (u32)f2bf(x0*c - x1*sn) | ((u32)f2bf(x0*sn + x1*c) << 16);
  x0 = bf2f(krt[ib]); x1 = bf2f(krt[ib+1]);
  *(u32*)&kf[ob+64] = (u32)f2bf(x0*c - x1*sn) | ((u32)f2bf(x0*sn + x1*c) << 16);
}

// noisy top-2 per token -> eids (i0|i1<<8), gates (g0,g1).  Deterministic.
__global__ void topk_k(const float* __restrict__ h2, const float* __restrict__ wr,
                       const float* __restrict__ br, const float* __restrict__ wn,
                       const float* __restrict__ bn, const float* __restrict__ noise,
                       int* __restrict__ eids, float2* __restrict__ gates)
{
  const int tok = blockIdx.x, t = threadIdx.x;
  const float4 xv = ((const float4*)(h2 + (long)tok*D_))[t];
  const float xs[4] = {xv.x, xv.y, xv.z, xv.w};
  float ar[8], an[8];
  #pragma unroll
  for (int e=0;e<8;e++){ ar[e]=0.f; an[e]=0.f; }
  #pragma unroll
  for (int i=0;i<4;i++){
    const int d = t*4+i;
    const float* wrr = wr + d*8;
    const float* wnr = wn + d*8;
    #pragma unroll
    for (int e=0;e<8;e++){ ar[e] += xs[i]*wrr[e]; an[e] += xs[i]*wnr[e]; }
  }
  #pragma unroll
  for (int e=0;e<8;e++){
    #pragma unroll
    for (int o=32;o>0;o>>=1){ ar[e] += __shfl_down(ar[e], o); an[e] += __shfl_down(an[e], o); }
  }
  __shared__ float rr[4][8], rn[4][8];
  if ((t&63)==0){
    const int w4 = t>>6;
    #pragma unroll
    for (int e=0;e<8;e++){ rr[w4][e]=ar[e]; rn[w4][e]=an[e]; }
  }
  __syncthreads();
  if (t==0){
    float nz[8];
    #pragma unroll
    for (int e=0;e<8;e++){
      const float r  = rr[0][e]+rr[1][e]+rr[2][e]+rr[3][e] + br[e];
      const float ns = rn[0][e]+rn[1][e]+rn[2][e]+rn[3][e] + bn[e];
      const float sp = (ns > 20.f) ? ns : log1pf(expf(ns));
      nz[e] = r + noise[(long)tok*8+e]*sp;
    }
    int i0 = 0;
    #pragma unroll
    for (int e=1;e<8;e++) if (nz[e] > nz[i0]) i0 = e;
    int i1 = -1; float best = -3.0e38f;
    #pragma unroll
    for (int e=0;e<8;e++) if (e != i0 && nz[e] > best){ best = nz[e]; i1 = e; }
    const float e1  = expf(nz[i1]-nz[i0]);
    const float inv = 1.f/(1.f+e1);
    eids[tok] = i0 | (i1 << 8);
    gates[tok] = make_float2(inv, e1*inv);
  }
}

// --- parallel deterministic compact: hist -> scan -> fill --------------------
__global__ void __launch_bounds__(64)
hist_k(const int* __restrict__ eids, int* __restrict__ segcnt)
{
  const int b = blockIdx.x, t = threadIdx.x;
  const int id = eids[b*64 + t];
  const int i0 = id & 255, i1 = (id >> 8) & 255;
  #pragma unroll
  for (int e=0;e<8;e++){
    const u64 m0 = __ballot(i0==e);
    const u64 m1 = __ballot(i1==e);
    if (t==0) segcnt[e*64+b] = __popcll(m0) + __popcll(m1);
  }
}

__global__ void __launch_bounds__(64)
scan_k(const int* __restrict__ segcnt, int* __restrict__ segoff,
       int* __restrict__ cntoff)
{
  const int t = threadIdx.x;
  int base = 0;
  for (int e=0;e<8;e++){
    const int c = segcnt[e*64+t];
    int sc = c;
    #pragma unroll
    for (int o=1;o<64;o<<=1){ int u = __shfl_up(sc, o); if (t >= o) sc += u; }
    const int tot = __shfl(sc, 63);
    segoff[e*64+t] = base + (sc - c);
    if (t==0){ cntoff[e] = tot; cntoff[8+e] = base; }
    base += tot;
  }
}

__global__ void __launch_bounds__(64)
fill_k(const int* __restrict__ eids, const float2* __restrict__ gates,
       const int* __restrict__ segoff, int* __restrict__ idxb,
       float* __restrict__ gvb, int* __restrict__ slotb)
{
  const int b = blockIdx.x, t = threadIdx.x;
  const int tok = b*64 + t;
  const int id = eids[tok];
  const int i0 = id & 255, i1 = (id >> 8) & 255;
  const float2 g = gates[tok];
  const u64 below = ((u64)1 << t) - 1;
  #pragma unroll
  for (int e=0;e<8;e++){
    const u64 m0 = __ballot(i0==e);
    const u64 m1 = __ballot(i1==e);
    if (i0==e){
      const int pos = segoff[e*64+b] + __popcll(m0 & below);
      idxb[pos] = tok; gvb[pos] = g.x; slotb[pos] = 0;
    } else if (i1==e){
      const int pos = segoff[e*64+b] + __popcll(m0) + __popcll(m1 & below);
      idxb[pos] = tok; gvb[pos] = g.y; slotb[pos] = 1;
    }
  }
}

// o = a + b
__global__ void addstore_k(const float* __restrict__ a, const float* __restrict__ b,
                           float* __restrict__ o, long n4)
{
  long i = (long)blockIdx.x*blockDim.x + threadIdx.x;
  const long stride = (long)gridDim.x*blockDim.x;
  for (; i<n4; i+=stride){
    const float4 va = ((const float4*)a)[i];
    const float4 vb = ((const float4*)b)[i];
    ((float4*)o)[i] = make_float4(va.x+vb.x, va.y+vb.y, va.z+vb.z, va.w+vb.w);
  }
}
// o += f0+f1+f2+f3
__global__ void addacc4_k(const float* __restrict__ f0, const float* __restrict__ f1,
                          const float* __restrict__ f2, const float* __restrict__ f3,
                          float* __restrict__ o, long n4)
{
  long i = (long)blockIdx.x*blockDim.x + threadIdx.x;
  const long stride = (long)gridDim.x*blockDim.x;
  for (; i<n4; i+=stride){
    const float4 a = ((const float4*)f0)[i];
    const float4 b = ((const float4*)f1)[i];
    const float4 c = ((const float4*)f2)[i];
    const float4 d = ((const float4*)f3)[i];
    float4 vo = ((const float4*)o)[i];
    ((float4*)o)[i] = make_float4(vo.x+a.x+b.x+c.x+d.x, vo.y+a.y+b.y+c.y+d.y,
                                  vo.z+a.z+b.z+c.z+d.z, vo.w+a.w+b.w+c.w+d.w);
  }
}

// ---------------------------------------------------------------------------
extern "C" void kernel_launch(void* const* d_in, const int* in_sizes, int n_in,
                              void* d_out, int out_size, void* d_ws, size_t ws_size,
                              hipStream_t stream)
{
  const float* x      = (const float*)d_in[0];
  const float* fcos   = (const float*)d_in[1];
  const float* fsin   = (const float*)d_in[2];
  const float* rnoise = (const float*)d_in[3];
  const float* rms1w  = (const float*)d_in[4];
  const float* rms2w  = (const float*)d_in[5];
  const float* w_lq   = (const float*)d_in[6];
  const float* w_lkv  = (const float*)d_in[7];
  const float* w_q    = (const float*)d_in[8];
  const float* w_k    = (const float*)d_in[9];
  const float* w_v    = (const float*)d_in[10];
  const float* w_qr   = (const float*)d_in[11];
  const float* b_qr   = (const float*)d_in[12];
  const float* w_kr   = (const float*)d_in[13];
  const float* b_kr   = (const float*)d_in[14];
  const float* w_o    = (const float*)d_in[15];
  const float* b_o    = (const float*)d_in[16];
  const float* w_route= (const float*)d_in[17];
  const float* b_route= (const float*)d_in[18];
  const float* w_noise= (const float*)d_in[19];
  const float* b_noise= (const float*)d_in[20];
  const float* rW1    = (const float*)d_in[21];
  const float* rb1    = (const float*)d_in[22];
  const float* rW2    = (const float*)d_in[23];
  const float* rb2    = (const float*)d_in[24];
  const float* sW1    = (const float*)d_in[25];
  const float* sb1    = (const float*)d_in[26];
  const float* sW2    = (const float*)d_in[27];
  const float* sb2    = (const float*)d_in[28];

  if (ws_size < 195166208ULL) return;

  char* ws = (char*)d_ws;
  // persistent / phased buffers
  u16*   h_bf    = (u16*)(ws + 0);           // P1
  u16*   cq_bf   = (u16*)(ws + 8388608);     // P1
  u16*   ckv_bf  = (u16*)(ws + 14680064);    // P1
  u16*   v_bf    = (u16*)(ws + 18874368);    // P1
  u16*   qf      = (u16*)(ws + 27262976);    // P1-P2, 16 MiB
  u16*   kf      = (u16*)(ws + 44040192);    // P1-P2, 16 MiB
  u16*   vt      = (u16*)(ws + 60817408);    // P1-P2, 8.25 MiB -> 69468160
  u16*   attn_bf = (u16*)(ws + 69468160);    // P2-P3, 8 MiB
  float* x1      = (float*)(ws + 77856768);  // P3 (dead after addstore)
  float* h2f     = (float*)(ws + 94633984);  // P3 (dead after addstore)
  u16*   h2_bf   = (u16*)(ws + 111411200);   // P3-P4, 8 MiB
  float* fb      = (float*)(ws + 119799808); // P4: 4 x 16 MiB partials -> 186908672
  u16*   Wt_g    = (u16*)(ws + 77856768);    // P4: 32 MiB (x1/h2f zone) -> 111411200
  int*   cntoff  = (int*)(ws + 189005824);   // 16 ints
  int*   eids    = (int*)(ws + 189006080);
  float2* gatesb = (float2*)(ws + 189022464);
  int*   idxb    = (int*)(ws + 189055232);
  float* gvb     = (float*)(ws + 189088000);
  int*   slotb   = (int*)(ws + 189120768);   // ends 189153536
  u16*   wo_t    = (u16*)(ws + 189153536);   // 2 MiB -> 191250560
  int*   segcnt  = (int*)(ws + 191250560);   // 2 KiB
  int*   segoff  = (int*)(ws + 191252608);   // 2 KiB
  // temporal overlays
  u16*   q_tmp   = (u16*)(ws + 77856768);    // P1
  u16*   qr_tmp  = (u16*)(ws + 86245376);
  u16*   k_tmp   = (u16*)(ws + 94633984);
  u16*   kr_tmp  = (u16*)(ws + 103022592);
  u16*   inter   = (u16*)(ws + 0);           // P4, 64 MiB (8192 x 4096 bf16)
  // small weight transposes (P1 zone, overlaid on fb region)
  u16*   wlq_t   = (u16*)(ws + 119799808);
  u16*   wlkv_t  = (u16*)(ws + 121372672);
  u16*   wq_t    = (u16*)(ws + 122421248);
  u16*   wqr_t   = (u16*)(ws + 123994112);
  u16*   wk_t    = (u16*)(ws + 125566976);
  u16*   wkr_t   = (u16*)(ws + 126615552);
  u16*   wv_t    = (u16*)(ws + 128712704);

  const dim3 blk(256,1,1);
  #define GEMM(FL, GRID, ...) gemm_k<FL><<<GRID, blk, 0, stream>>>(__VA_ARGS__)
  #define NOSPARSE nullptr,nullptr,nullptr,nullptr,nullptr,nullptr,nullptr,0

  // P0: small weight transposes (f32 [K][N] -> bf16 [N][K])
  tpose_k<<<dim3(24,32),blk,0,stream>>>(w_lq,  wlq_t, 1024, 768, 0,0);
  tpose_k<<<dim3(16,32),blk,0,stream>>>(w_lkv, wlkv_t,1024, 512, 0,0);
  tpose_k<<<dim3(32,24),blk,0,stream>>>(w_q,   wq_t,   768,1024, 0,0);
  tpose_k<<<dim3(32,24),blk,0,stream>>>(w_qr,  wqr_t,  768,1024, 0,0);
  tpose_k<<<dim3(32,16),blk,0,stream>>>(w_k,   wk_t,   512,1024, 0,0);
  tpose_k<<<dim3(32,32),blk,0,stream>>>(w_kr,  wkr_t, 1024,1024, 0,0);
  tpose_k<<<dim3(32,16),blk,0,stream>>>(w_v,   wv_t,   512,1024, 0,0);
  tpose_k<<<dim3(32,32),blk,0,stream>>>(w_o,   wo_t,  1024,1024, 0,0);

  // P1: rmsnorm + projections + rope
  rmsnorm_k<false><<<NTOK, blk, 0, stream>>>(x, rms1w, h_bf, nullptr);

  GEMM(F_OUTBF16, dim3(6,32,1),  h_bf,1024,0,  wlq_t,1024,0,  cq_bf,768,0,  NOSPARSE, 1024, 768);
  GEMM(F_OUTBF16, dim3(4,32,1),  h_bf,1024,0,  wlkv_t,1024,0, ckv_bf,512,0, NOSPARSE, 1024, 512);
  GEMM(F_OUTBF16, dim3(8,32,1),  cq_bf,768,0,  wq_t,768,0,    q_tmp,1024,0, NOSPARSE, 768, 1024);
  GEMM(F_OUTBF16|F_BIAS, dim3(8,32,1), cq_bf,768,0, wqr_t,768,0, qr_tmp,1024,0,
       nullptr, b_qr, nullptr,nullptr,nullptr,nullptr,nullptr,0, 768, 1024);
  GEMM(F_OUTBF16, dim3(8,32,1),  ckv_bf,512,0, wk_t,512,0,    k_tmp,1024,0, NOSPARSE, 512, 1024);
  GEMM(F_OUTBF16|F_BIAS, dim3(8,32,1), h_bf,1024,0, wkr_t,1024,0, kr_tmp,1024,0,
       nullptr, b_kr, nullptr,nullptr,nullptr,nullptr,nullptr,0, 1024, 1024);
  GEMM(F_OUTBF16, dim3(8,32,1),  ckv_bf,512,0, wv_t,512,0,    v_bf,1024,0,  NOSPARSE, 512, 1024);

  rope_concat_k<<<8192, blk, 0, stream>>>(q_tmp, qr_tmp, k_tmp, kr_tmp, fcos, fsin, qf, kf);
  vt_k<<<dim3(64,2,32), blk, 0, stream>>>(v_bf, vt);

  // P2: flash attention (fused QK -> online softmax -> PV)
  flash_k<<<dim3(32,16), blk, 0, stream>>>(qf, kf, vt, attn_bf);

  // P3: o-proj + rmsnorm2 + router
  GEMM(F_BIAS|F_RESID, dim3(8,32,1), attn_bf,1024,0, wo_t,1024,0, x1,1024,0,
       nullptr, b_o, x, nullptr,nullptr,nullptr,nullptr,0, 1024, 1024);
  rmsnorm_k<true><<<NTOK, blk, 0, stream>>>(x1, rms2w, h2_bf, h2f);
  topk_k<<<NTOK, blk, 0, stream>>>(h2f, w_route, b_route, w_noise, b_noise, rnoise,
                                   eids, gatesb);
  hist_k<<<64, 64, 0, stream>>>(eids, segcnt);
  scan_k<<<1, 64, 0, stream>>>(segcnt, segoff, cntoff);
  fill_k<<<64, 64, 0, stream>>>(eids, gatesb, segoff, idxb, gvb, slotb);
  addstore_k<<<2048, blk, 0, stream>>>(x1, h2f, (float*)d_out, 1048576L);  // out = x1+h2
  hipMemsetAsync(fb, 0, 67108864, stream);   // zero 4x16MiB partials

  // P4a: routed experts, 2 groups of 4; G2 split-K x2 into fb[slot*2+kh]
  for (int g=0; g<2; ++g){
    const int eb = g*4;
    tpose_k<<<dim3(128,32,4),blk,0,stream>>>(rW1 + (long)eb*4194304, Wt_g, 1024, 4096,
                                             4194304L, 4194304L);
    GEMM(F_OUTBF16|F_BIAS|F_RELU|F_GATHER|F_EXPB, dim3(32,32,4),
         h2_bf,1024,0, Wt_g,1024,4194304L, inter,4096,0,
         nullptr, rb1, nullptr, nullptr, idxb, nullptr, cntoff, eb, 1024, 4096);
    tpose_k<<<dim3(32,128,4),blk,0,stream>>>(rW2 + (long)eb*4194304, Wt_g, 4096, 1024,
                                             4194304L, 4194304L);
    GEMM(F_BIAS|F_SCATTER|F_EXPB|F_SPLITK2, dim3(8,32,8),
         inter,4096,0, Wt_g,4096,4194304L, fb,1024,4194304L,
         nullptr, rb2, nullptr, gvb, idxb, slotb, cntoff, eb, 2048, 1024);
  }

  // P4b: shared experts, dense; G2 split-K x2, += into fb[j*2+kh]
  for (int j=0;j<2;j++){
    tpose_k<<<dim3(128,32,1),blk,0,stream>>>(sW1 + (long)j*4194304, Wt_g, 1024, 4096, 0,0);
    GEMM(F_OUTBF16|F_BIAS|F_RELU, dim3(32,32,1), h2_bf,1024,0, Wt_g,1024,0, inter,4096,0,
         nullptr, sb1 + j*4096, nullptr,nullptr,nullptr,nullptr,nullptr,0, 1024, 4096);
    tpose_k<<<dim3(32,128,1),blk,0,stream>>>(sW2 + (long)j*4194304, Wt_g, 4096, 1024, 0,0);
    GEMM(F_BIAS|F_GATEACC|F_SPLITK2, dim3(8,32,2),
         inter,4096,0, Wt_g,4096,0, fb + (long)j*2*4194304L,1024,4194304L,
         nullptr, sb2 + j*1024, nullptr,nullptr,nullptr,nullptr,nullptr,0, 2048, 1024);
  }

  // out += fb0+fb1+fb2+fb3
  addacc4_k<<<2048, blk, 0, stream>>>(fb, fb+4194304L, fb+8388608L, fb+12582912L,
                                      (float*)d_out, 1048576L);
}